// Round 1
// baseline (624.282 us; speedup 1.0000x reference)
//
#include <hip/hip_runtime.h>
#include <cstdint>
#include <cstddef>

namespace {

constexpr int NN = 100000;   // nodes
constexpr int NE = 1600000;  // edges
constexpr int DI = 256;
constexpr int DH = 128;
constexpr int DO = 64;
constexpr int SCAN_CHUNK = 1024;
constexpr int SCAN_NB = (NN + SCAN_CHUNK - 1) / SCAN_CHUNK;  // 98

// ---------------- CSR build ----------------
__global__ __launch_bounds__(256) void k_hist(const int* __restrict__ erow,
                                              const int* __restrict__ ecol,
                                              const float* __restrict__ eval,
                                              int* __restrict__ cnt,
                                              float* __restrict__ cw) {
  const int e = blockIdx.x * 256 + threadIdx.x;  // grid exact: NE
  atomicAdd(&cnt[erow[e]], 1);
  atomicAdd(&cw[ecol[e]], eval[e]);
}

__global__ __launch_bounds__(256) void k_scan1(const int* __restrict__ cnt,
                                               int* __restrict__ bsum) {
  __shared__ int red[256];
  const int b = blockIdx.x, t = threadIdx.x;
  const int base = b * SCAN_CHUNK + t * 4;
  int s = 0;
#pragma unroll
  for (int j = 0; j < 4; ++j) {
    const int idx = base + j;
    if (idx < NN) s += cnt[idx];
  }
  red[t] = s;
  __syncthreads();
  for (int off = 128; off > 0; off >>= 1) {
    if (t < off) red[t] += red[t + off];
    __syncthreads();
  }
  if (t == 0) bsum[b] = red[0];
}

__global__ __launch_bounds__(128) void k_scan2(const int* __restrict__ bsum,
                                               int* __restrict__ boff,
                                               int* __restrict__ rowptr) {
  __shared__ int s[128];
  const int t = threadIdx.x;
  const int v = (t < SCAN_NB) ? bsum[t] : 0;
  s[t] = v;
  __syncthreads();
  for (int off = 1; off < 128; off <<= 1) {
    int x = 0;
    if (t >= off) x = s[t - off];
    __syncthreads();
    s[t] += x;
    __syncthreads();
  }
  if (t < SCAN_NB) boff[t] = s[t] - v;   // exclusive block offsets
  if (t == 127) rowptr[NN] = s[127];     // total == NE
}

__global__ __launch_bounds__(256) void k_scan3(const int* __restrict__ cnt,
                                               const int* __restrict__ boff,
                                               int* __restrict__ rowptr,
                                               int* __restrict__ cursor) {
  __shared__ int tsum[256];
  const int b = blockIdx.x, t = threadIdx.x;
  const int base = b * SCAN_CHUNK + t * 4;
  int v[4];
#pragma unroll
  for (int j = 0; j < 4; ++j) {
    const int idx = base + j;
    v[j] = (idx < NN) ? cnt[idx] : 0;
  }
  const int pre1 = v[0];
  const int pre2 = pre1 + v[1];
  const int pre3 = pre2 + v[2];
  const int s = pre3 + v[3];
  tsum[t] = s;
  __syncthreads();
  for (int off = 1; off < 256; off <<= 1) {
    int x = 0;
    if (t >= off) x = tsum[t - off];
    __syncthreads();
    tsum[t] += x;
    __syncthreads();
  }
  const int excl = tsum[t] - s + boff[b];
  const int w[4] = {excl, excl + pre1, excl + pre2, excl + pre3};
#pragma unroll
  for (int j = 0; j < 4; ++j) {
    const int idx = base + j;
    if (idx < NN) { rowptr[idx] = w[j]; cursor[idx] = w[j]; }
  }
}

__global__ __launch_bounds__(256) void k_scatter(const int* __restrict__ erow,
                                                 const int* __restrict__ ecol,
                                                 const float* __restrict__ eval,
                                                 int* __restrict__ cursor,
                                                 int* __restrict__ ccol,
                                                 float* __restrict__ cval) {
  const int e = blockIdx.x * 256 + threadIdx.x;  // grid exact: NE
  const int r = erow[e];
  const int pos = atomicAdd(&cursor[r], 1);
  ccol[pos] = ecol[e];
  cval[pos] = eval[e];
}

// ---------------- GEMM (f32 vector, register-tiled) ----------------
template <int BM, int BN, int BK, int TM, int TN>
__global__ __launch_bounds__(256) void k_gemm(const float* __restrict__ A,
                                              const float* __restrict__ B,
                                              float* __restrict__ C,
                                              int M, int K, int N) {
  constexpr int NT = (BM / TM) * (BN / TN);
  static_assert(NT == 256, "thread count must be 256");
  constexpr int BMP = BM + 4;  // pad: conflict-light transposed stores, keeps 16B align
  __shared__ float As[BK][BMP];  // transposed A tile: As[k][m]
  __shared__ float Bs[BK][BN];
  const int tid = threadIdx.x;
  const int tn = tid % (BN / TN);
  const int tm = tid / (BN / TN);
  const int row0 = blockIdx.x * BM;

  float acc[TM][TN];
#pragma unroll
  for (int m = 0; m < TM; ++m)
#pragma unroll
    for (int n = 0; n < TN; ++n) acc[m][n] = 0.f;

  for (int k0 = 0; k0 < K; k0 += BK) {
#pragma unroll
    for (int i = tid; i < BM * (BK / 4); i += NT) {
      const int m = i / (BK / 4);
      const int kc = i % (BK / 4);
      int row = row0 + m;
      if (row >= M) row = M - 1;  // clamp: loads harmless, stores guarded
      const float4 a = *reinterpret_cast<const float4*>(&A[(size_t)row * K + k0 + kc * 4]);
      As[kc * 4 + 0][m] = a.x;
      As[kc * 4 + 1][m] = a.y;
      As[kc * 4 + 2][m] = a.z;
      As[kc * 4 + 3][m] = a.w;
    }
#pragma unroll
    for (int i = tid; i < BK * (BN / 4); i += NT) {
      const int kr = i / (BN / 4);
      const int nc = i % (BN / 4);
      *reinterpret_cast<float4*>(&Bs[kr][nc * 4]) =
          *reinterpret_cast<const float4*>(&B[(size_t)(k0 + kr) * N + nc * 4]);
    }
    __syncthreads();
#pragma unroll
    for (int kk = 0; kk < BK; ++kk) {
      float av[TM], bv[TN];
#pragma unroll
      for (int m = 0; m < TM; m += 4)
        *reinterpret_cast<float4*>(&av[m]) =
            *reinterpret_cast<const float4*>(&As[kk][tm * TM + m]);
#pragma unroll
      for (int n = 0; n < TN; n += 4)
        *reinterpret_cast<float4*>(&bv[n]) =
            *reinterpret_cast<const float4*>(&Bs[kk][tn * TN + n]);
#pragma unroll
      for (int m = 0; m < TM; ++m)
#pragma unroll
        for (int n = 0; n < TN; ++n) acc[m][n] = fmaf(av[m], bv[n], acc[m][n]);
    }
    __syncthreads();
  }
#pragma unroll
  for (int m = 0; m < TM; ++m) {
    const int row = row0 + tm * TM + m;
    if (row < M) {
#pragma unroll
      for (int n = 0; n < TN; n += 4) {
        float4 o;
        o.x = acc[m][n + 0]; o.y = acc[m][n + 1];
        o.z = acc[m][n + 2]; o.w = acc[m][n + 3];
        *reinterpret_cast<float4*>(&C[(size_t)row * N + tn * TN + n]) = o;
      }
    }
  }
}

// ---------------- w2sum[k] = sum_d W2[k][d] ----------------
__global__ void k_w2sum(const float* __restrict__ W2, float* __restrict__ w2s) {
  const int k = threadIdx.x;  // 128 threads
  float s = 0.f;
  for (int d = 0; d < DO; ++d) s += W2[k * DO + d];
  w2s[k] = s;
}

// ---------------- SPMM1 + relu + hw (half-wave per row) ----------------
__global__ __launch_bounds__(256) void k_spmm1(const float* __restrict__ sup1,
                                               const int* __restrict__ rowptr,
                                               const int* __restrict__ ccol,
                                               const float* __restrict__ cval,
                                               const float* __restrict__ w2s,
                                               float* __restrict__ h1,
                                               float* __restrict__ hw) {
  const int r = blockIdx.x * 8 + (threadIdx.x >> 5);  // grid exact: NN/8
  const int lane = threadIdx.x & 31;                  // 32 lanes x float4 = 128 ch
  const int e0 = rowptr[r];
  const int e1 = rowptr[r + 1];
  const float4* s4 = reinterpret_cast<const float4*>(sup1);
  float ax = 0.f, ay = 0.f, az = 0.f, aw = 0.f;
  for (int e = e0; e < e1; ++e) {
    const int c = ccol[e];
    const float v = cval[e];
    const float4 sv = s4[(size_t)c * 32 + lane];
    ax = fmaf(v, sv.x, ax); ay = fmaf(v, sv.y, ay);
    az = fmaf(v, sv.z, az); aw = fmaf(v, sv.w, aw);
  }
  ax = fmaxf(ax, 0.f); ay = fmaxf(ay, 0.f);
  az = fmaxf(az, 0.f); aw = fmaxf(aw, 0.f);
  float4 o; o.x = ax; o.y = ay; o.z = az; o.w = aw;
  reinterpret_cast<float4*>(h1)[(size_t)r * 32 + lane] = o;
  // hw[r] = relu_row . w2sum  (feeds the folded z_mu)
  const float4 w = reinterpret_cast<const float4*>(w2s)[lane];
  float p = ax * w.x + ay * w.y + az * w.z + aw * w.w;
  for (int off = 16; off > 0; off >>= 1) p += __shfl_down(p, off, 32);
  if (lane == 0) hw[r] = p;
}

// ---------------- SPMM3 + exp + reduce (16 lanes per row) ----------------
__global__ __launch_bounds__(256) void k_spmm3(const float* __restrict__ sup3,
                                               const int* __restrict__ rowptr,
                                               const int* __restrict__ ccol,
                                               const float* __restrict__ cval,
                                               float* __restrict__ pexp) {
  const int r = blockIdx.x * 16 + (threadIdx.x >> 4);  // grid exact: NN/16
  const int lane = threadIdx.x & 15;                   // 16 lanes x float4 = 64 ch
  const int e0 = rowptr[r];
  const int e1 = rowptr[r + 1];
  const float4* s4 = reinterpret_cast<const float4*>(sup3);
  float ax = 0.f, ay = 0.f, az = 0.f, aw = 0.f;
  for (int e = e0; e < e1; ++e) {
    const int c = ccol[e];
    const float v = cval[e];
    const float4 sv = s4[(size_t)c * 16 + lane];
    ax = fmaf(v, sv.x, ax); ay = fmaf(v, sv.y, ay);
    az = fmaf(v, sv.z, az); aw = fmaf(v, sv.w, aw);
  }
  float p = expf(ax) + expf(ay) + expf(az) + expf(aw);
  for (int off = 8; off > 0; off >>= 1) p += __shfl_down(p, off, 16);
  __shared__ float part[16];
  if (lane == 0) part[threadIdx.x >> 4] = p;
  __syncthreads();
  if (threadIdx.x == 0) {
    float s = 0.f;
#pragma unroll
    for (int i = 0; i < 16; ++i) s += part[i];
    pexp[blockIdx.x] = s;
  }
}

// ---------------- z_mu partial dot: cw . hw ----------------
__global__ __launch_bounds__(256) void k_zmu(const float* __restrict__ cw,
                                             const float* __restrict__ hw,
                                             float* __restrict__ pzmu) {
  __shared__ float red[256];
  const int i = blockIdx.x * 256 + threadIdx.x;
  red[threadIdx.x] = (i < NN) ? cw[i] * hw[i] : 0.f;
  __syncthreads();
  for (int off = 128; off > 0; off >>= 1) {
    if (threadIdx.x < off) red[threadIdx.x] += red[threadIdx.x + off];
    __syncthreads();
  }
  if (threadIdx.x == 0) pzmu[blockIdx.x] = red[0];
}

// ---------------- finalize ----------------
__global__ __launch_bounds__(256) void k_final(const float* __restrict__ pzmu, int nz,
                                               const float* __restrict__ pexp, int ne,
                                               float* __restrict__ out) {
  __shared__ float red[256];
  const int t = threadIdx.x;
  float s1 = 0.f, s2 = 0.f;
  for (int i = t; i < nz; i += 256) s1 += pzmu[i];
  for (int i = t; i < ne; i += 256) s2 += pexp[i];
  red[t] = s1;
  __syncthreads();
  for (int off = 128; off > 0; off >>= 1) {
    if (t < off) red[t] += red[t + off];
    __syncthreads();
  }
  const float tot1 = red[0];
  __syncthreads();
  red[t] = s2;
  __syncthreads();
  for (int off = 128; off > 0; off >>= 1) {
    if (t < off) red[t] += red[t + off];
    __syncthreads();
  }
  if (t == 0) {
    const float denom = (float)NN * (float)DO;  // mean over [N, 64]
    out[0] = tot1 / denom;
    out[1] = logf(red[0] / denom);
  }
}

}  // namespace

extern "C" void kernel_launch(void* const* d_in, const int* in_sizes, int n_in,
                              void* d_out, int out_size, void* d_ws, size_t ws_size,
                              hipStream_t stream) {
  const float* x    = (const float*)d_in[0];
  const int*   erow = (const int*)d_in[1];
  const int*   ecol = (const int*)d_in[2];
  const float* eval = (const float*)d_in[3];
  const float* W1   = (const float*)d_in[4];
  const float* W2   = (const float*)d_in[5];
  const float* W3   = (const float*)d_in[6];
  float* out = (float*)d_out;

  // workspace carve-out (all 256B aligned); peak ~117 MB
  char* p = (char*)d_ws;
  auto alloc = [&](size_t bytes) -> void* {
    void* r = (void*)p;
    p += (bytes + 255) & ~(size_t)255;
    return r;
  };
  float* bufA   = (float*)alloc((size_t)NN * DH * 4);  // support1, reused as support3
  float* h1     = (float*)alloc((size_t)NN * DH * 4);
  float* cval   = (float*)alloc((size_t)NE * 4);
  int*   ccol   = (int*)alloc((size_t)NE * 4);
  int*   rowptr = (int*)alloc((size_t)(NN + 1) * 4);
  int*   cursor = (int*)alloc((size_t)NN * 4);
  int*   cnt    = (int*)alloc((size_t)NN * 4);
  float* cw     = (float*)alloc((size_t)NN * 4);
  float* hw     = (float*)alloc((size_t)NN * 4);
  float* w2s    = (float*)alloc(DH * 4);
  int*   bsum   = (int*)alloc(SCAN_NB * 4);
  int*   boff   = (int*)alloc(SCAN_NB * 4);
  float* pexp   = (float*)alloc(6250 * 4);
  float* pzmu   = (float*)alloc(391 * 4);

  hipMemsetAsync(cnt, 0, (size_t)NN * 4, stream);
  hipMemsetAsync(cw, 0, (size_t)NN * 4, stream);

  // CSR build (reused by both SPMMs)
  k_hist<<<NE / 256, 256, 0, stream>>>(erow, ecol, eval, cnt, cw);
  k_scan1<<<SCAN_NB, 256, 0, stream>>>(cnt, bsum);
  k_scan2<<<1, 128, 0, stream>>>(bsum, boff, rowptr);
  k_scan3<<<SCAN_NB, 256, 0, stream>>>(cnt, boff, rowptr, cursor);
  k_scatter<<<NE / 256, 256, 0, stream>>>(erow, ecol, eval, cursor, ccol, cval);

  // layer 1: support1 = x @ W1
  k_gemm<128, 128, 16, 8, 8><<<(NN + 127) / 128, 256, 0, stream>>>(x, W1, bufA, NN, DI, DH);
  k_w2sum<<<1, 128, 0, stream>>>(W2, w2s);
  // h1 = relu(spmm(support1)); hw = h1 . w2sum   (mu branch folded)
  k_spmm1<<<NN / 8, 256, 0, stream>>>(bufA, rowptr, ccol, cval, w2s, h1, hw);

  // layer 2 (logvar only): support3 = h1 @ W3
  k_gemm<128, 64, 16, 8, 4><<<(NN + 127) / 128, 256, 0, stream>>>(h1, W3, bufA, NN, DH, DO);
  // logvar spmm fused with sum(exp(.)) -> per-block partials
  k_spmm3<<<NN / 16, 256, 0, stream>>>(bufA, rowptr, ccol, cval, pexp);

  // z_mu = (cw . hw) / (N*64)
  k_zmu<<<(NN + 255) / 256, 256, 0, stream>>>(cw, hw, pzmu);
  k_final<<<1, 256, 0, stream>>>(pzmu, (NN + 255) / 256, pexp, NN / 16, out);
}

// Round 2
// 444.253 us; speedup vs baseline: 1.4052x; 1.4052x over previous
//
#include <hip/hip_runtime.h>
#include <cstdint>
#include <cstddef>

namespace {

constexpr int NN = 100000;   // nodes
constexpr int NE = 1600000;  // edges
constexpr int DI = 256;
constexpr int DH = 128;
constexpr int DO = 64;
constexpr int SCAN_CHUNK = 1024;
constexpr int SCAN_NB = (NN + SCAN_CHUNK - 1) / SCAN_CHUNK;  // 98

__device__ inline float bf2f(unsigned short h) {
  return __uint_as_float((unsigned int)h << 16);
}
__device__ inline unsigned short f2bf(float f) {
  unsigned int u = __float_as_uint(f);
  u += 0x7FFFu + ((u >> 16) & 1u);  // round-to-nearest-even
  return (unsigned short)(u >> 16);
}

// ---------------- CSR build: one atomic per edge total ----------------
// rank[e] = position of edge e within its row (atomic counter return value)
__global__ __launch_bounds__(256) void k_rank(const int* __restrict__ erow,
                                              int* __restrict__ cnt,
                                              int* __restrict__ rank) {
  const int e = blockIdx.x * 256 + threadIdx.x;  // grid exact: NE
  rank[e] = atomicAdd(&cnt[erow[e]], 1);
}

__global__ __launch_bounds__(256) void k_scan1(const int* __restrict__ cnt,
                                               int* __restrict__ bsum) {
  __shared__ int red[256];
  const int b = blockIdx.x, t = threadIdx.x;
  const int base = b * SCAN_CHUNK + t * 4;
  int s = 0;
#pragma unroll
  for (int j = 0; j < 4; ++j) {
    const int idx = base + j;
    if (idx < NN) s += cnt[idx];
  }
  red[t] = s;
  __syncthreads();
  for (int off = 128; off > 0; off >>= 1) {
    if (t < off) red[t] += red[t + off];
    __syncthreads();
  }
  if (t == 0) bsum[b] = red[0];
}

__global__ __launch_bounds__(128) void k_scan2(const int* __restrict__ bsum,
                                               int* __restrict__ boff,
                                               int* __restrict__ rowptr) {
  __shared__ int s[128];
  const int t = threadIdx.x;
  const int v = (t < SCAN_NB) ? bsum[t] : 0;
  s[t] = v;
  __syncthreads();
  for (int off = 1; off < 128; off <<= 1) {
    int x = 0;
    if (t >= off) x = s[t - off];
    __syncthreads();
    s[t] += x;
    __syncthreads();
  }
  if (t < SCAN_NB) boff[t] = s[t] - v;   // exclusive block offsets
  if (t == 127) rowptr[NN] = s[127];     // total == NE
}

__global__ __launch_bounds__(256) void k_scan3(const int* __restrict__ cnt,
                                               const int* __restrict__ boff,
                                               int* __restrict__ rowptr) {
  __shared__ int tsum[256];
  const int b = blockIdx.x, t = threadIdx.x;
  const int base = b * SCAN_CHUNK + t * 4;
  int v[4];
#pragma unroll
  for (int j = 0; j < 4; ++j) {
    const int idx = base + j;
    v[j] = (idx < NN) ? cnt[idx] : 0;
  }
  const int pre1 = v[0];
  const int pre2 = pre1 + v[1];
  const int pre3 = pre2 + v[2];
  const int s = pre3 + v[3];
  tsum[t] = s;
  __syncthreads();
  for (int off = 1; off < 256; off <<= 1) {
    int x = 0;
    if (t >= off) x = tsum[t - off];
    __syncthreads();
    tsum[t] += x;
    __syncthreads();
  }
  const int excl = tsum[t] - s + boff[b];
  const int w[4] = {excl, excl + pre1, excl + pre2, excl + pre3};
#pragma unroll
  for (int j = 0; j < 4; ++j) {
    const int idx = base + j;
    if (idx < NN) rowptr[idx] = w[j];
  }
}

// atomic-free placement: pos = rowptr[row] + rank
__global__ __launch_bounds__(256) void k_place(const int* __restrict__ erow,
                                               const int* __restrict__ ecol,
                                               const float* __restrict__ eval,
                                               const int* __restrict__ rank,
                                               const int* __restrict__ rowptr,
                                               int* __restrict__ ccol,
                                               float* __restrict__ cval) {
  const int e = blockIdx.x * 256 + threadIdx.x;  // grid exact: NE
  const int pos = rowptr[erow[e]] + rank[e];
  ccol[pos] = ecol[e];
  cval[pos] = eval[e];
}

// ---------------- GEMM (f32 vector, register-tiled, bf16 output) ----------
template <int BM, int BN, int BK, int TM, int TN>
__global__ __launch_bounds__(256) void k_gemm(const float* __restrict__ A,
                                              const float* __restrict__ B,
                                              unsigned short* __restrict__ C,
                                              int M, int K, int N) {
  constexpr int NT = (BM / TM) * (BN / TN);
  static_assert(NT == 256, "thread count must be 256");
  constexpr int BMP = BM + 4;
  __shared__ float As[BK][BMP];  // transposed A tile: As[k][m]
  __shared__ float Bs[BK][BN];
  const int tid = threadIdx.x;
  const int tn = tid % (BN / TN);
  const int tm = tid / (BN / TN);
  const int row0 = blockIdx.x * BM;

  float acc[TM][TN];
#pragma unroll
  for (int m = 0; m < TM; ++m)
#pragma unroll
    for (int n = 0; n < TN; ++n) acc[m][n] = 0.f;

  for (int k0 = 0; k0 < K; k0 += BK) {
#pragma unroll
    for (int i = tid; i < BM * (BK / 4); i += NT) {
      const int m = i / (BK / 4);
      const int kc = i % (BK / 4);
      int row = row0 + m;
      if (row >= M) row = M - 1;  // clamp: loads harmless, stores guarded
      const float4 a = *reinterpret_cast<const float4*>(&A[(size_t)row * K + k0 + kc * 4]);
      As[kc * 4 + 0][m] = a.x;
      As[kc * 4 + 1][m] = a.y;
      As[kc * 4 + 2][m] = a.z;
      As[kc * 4 + 3][m] = a.w;
    }
#pragma unroll
    for (int i = tid; i < BK * (BN / 4); i += NT) {
      const int kr = i / (BN / 4);
      const int nc = i % (BN / 4);
      *reinterpret_cast<float4*>(&Bs[kr][nc * 4]) =
          *reinterpret_cast<const float4*>(&B[(size_t)(k0 + kr) * N + nc * 4]);
    }
    __syncthreads();
#pragma unroll
    for (int kk = 0; kk < BK; ++kk) {
      float av[TM], bv[TN];
#pragma unroll
      for (int m = 0; m < TM; m += 4)
        *reinterpret_cast<float4*>(&av[m]) =
            *reinterpret_cast<const float4*>(&As[kk][tm * TM + m]);
#pragma unroll
      for (int n = 0; n < TN; n += 4)
        *reinterpret_cast<float4*>(&bv[n]) =
            *reinterpret_cast<const float4*>(&Bs[kk][tn * TN + n]);
#pragma unroll
      for (int m = 0; m < TM; ++m)
#pragma unroll
        for (int n = 0; n < TN; ++n) acc[m][n] = fmaf(av[m], bv[n], acc[m][n]);
    }
    __syncthreads();
  }
#pragma unroll
  for (int m = 0; m < TM; ++m) {
    const int row = row0 + tm * TM + m;
    if (row < M) {
#pragma unroll
      for (int n = 0; n < TN; n += 4) {
        ushort4 o;
        o.x = f2bf(acc[m][n + 0]);
        o.y = f2bf(acc[m][n + 1]);
        o.z = f2bf(acc[m][n + 2]);
        o.w = f2bf(acc[m][n + 3]);
        *reinterpret_cast<ushort4*>(&C[(size_t)row * N + tn * TN + n]) = o;
      }
    }
  }
}

// ---------------- w2sum[k] = sum_d W2[k][d] ----------------
__global__ void k_w2sum(const float* __restrict__ W2, float* __restrict__ w2s) {
  const int k = threadIdx.x;  // 128 threads
  float s = 0.f;
  for (int d = 0; d < DO; ++d) s += W2[k * DO + d];
  w2s[k] = s;
}

// ---------------- SPMM1 (bf16 gather) + relu + hw ----------------
__global__ __launch_bounds__(256) void k_spmm1(const unsigned short* __restrict__ sup1,
                                               const int* __restrict__ rowptr,
                                               const int* __restrict__ ccol,
                                               const float* __restrict__ cval,
                                               const float* __restrict__ w2s,
                                               float* __restrict__ h1,
                                               float* __restrict__ hw) {
  const int r = blockIdx.x * 8 + (threadIdx.x >> 5);  // grid exact: NN/8
  const int lane = threadIdx.x & 31;                  // 32 lanes x 4ch = 128 ch
  const int e0 = rowptr[r];
  const int e1 = rowptr[r + 1];
  const ushort4* s4 = reinterpret_cast<const ushort4*>(sup1);  // 8B = 4 bf16
  float ax = 0.f, ay = 0.f, az = 0.f, aw = 0.f;
  for (int e = e0; e < e1; ++e) {
    const int c = ccol[e];
    const float v = cval[e];
    const ushort4 sv = s4[(size_t)c * 32 + lane];
    ax = fmaf(v, bf2f(sv.x), ax); ay = fmaf(v, bf2f(sv.y), ay);
    az = fmaf(v, bf2f(sv.z), az); aw = fmaf(v, bf2f(sv.w), aw);
  }
  ax = fmaxf(ax, 0.f); ay = fmaxf(ay, 0.f);
  az = fmaxf(az, 0.f); aw = fmaxf(aw, 0.f);
  float4 o; o.x = ax; o.y = ay; o.z = az; o.w = aw;
  reinterpret_cast<float4*>(h1)[(size_t)r * 32 + lane] = o;
  // hw[r] = relu_row . w2sum  (feeds the folded z_mu)
  const float4 w = reinterpret_cast<const float4*>(w2s)[lane];
  float p = ax * w.x + ay * w.y + az * w.z + aw * w.w;
  for (int off = 16; off > 0; off >>= 1) p += __shfl_down(p, off, 32);
  if (lane == 0) hw[r] = p;
}

// ---------------- SPMM3 (bf16 gather) + exp + reduce ----------------
__global__ __launch_bounds__(256) void k_spmm3(const unsigned short* __restrict__ sup3,
                                               const int* __restrict__ rowptr,
                                               const int* __restrict__ ccol,
                                               const float* __restrict__ cval,
                                               float* __restrict__ pexp) {
  const int r = blockIdx.x * 16 + (threadIdx.x >> 4);  // grid exact: NN/16
  const int lane = threadIdx.x & 15;                   // 16 lanes x 4ch = 64 ch
  const int e0 = rowptr[r];
  const int e1 = rowptr[r + 1];
  const ushort4* s4 = reinterpret_cast<const ushort4*>(sup3);
  float ax = 0.f, ay = 0.f, az = 0.f, aw = 0.f;
  for (int e = e0; e < e1; ++e) {
    const int c = ccol[e];
    const float v = cval[e];
    const ushort4 sv = s4[(size_t)c * 16 + lane];
    ax = fmaf(v, bf2f(sv.x), ax); ay = fmaf(v, bf2f(sv.y), ay);
    az = fmaf(v, bf2f(sv.z), az); aw = fmaf(v, bf2f(sv.w), aw);
  }
  float p = expf(ax) + expf(ay) + expf(az) + expf(aw);
  for (int off = 8; off > 0; off >>= 1) p += __shfl_down(p, off, 16);
  __shared__ float part[16];
  if (lane == 0) part[threadIdx.x >> 4] = p;
  __syncthreads();
  if (threadIdx.x == 0) {
    float s = 0.f;
#pragma unroll
    for (int i = 0; i < 16; ++i) s += part[i];
    pexp[blockIdx.x] = s;
  }
}

// ---------------- z_mu partials: sum_e val_e * hw[col_e] ----------------
__global__ __launch_bounds__(256) void k_edot(const int* __restrict__ ecol,
                                              const float* __restrict__ eval,
                                              const float* __restrict__ hw,
                                              float* __restrict__ pzmu) {
  __shared__ float red[256];
  const int i = blockIdx.x * 256 + threadIdx.x;  // grid exact: NE/256
  red[threadIdx.x] = eval[i] * hw[ecol[i]];
  __syncthreads();
  for (int off = 128; off > 0; off >>= 1) {
    if (threadIdx.x < off) red[threadIdx.x] += red[threadIdx.x + off];
    __syncthreads();
  }
  if (threadIdx.x == 0) pzmu[blockIdx.x] = red[0];
}

// ---------------- finalize ----------------
__global__ __launch_bounds__(256) void k_final(const float* __restrict__ pzmu, int nz,
                                               const float* __restrict__ pexp, int ne,
                                               float* __restrict__ out) {
  __shared__ float red[256];
  const int t = threadIdx.x;
  float s1 = 0.f, s2 = 0.f;
  for (int i = t; i < nz; i += 256) s1 += pzmu[i];
  for (int i = t; i < ne; i += 256) s2 += pexp[i];
  red[t] = s1;
  __syncthreads();
  for (int off = 128; off > 0; off >>= 1) {
    if (t < off) red[t] += red[t + off];
    __syncthreads();
  }
  const float tot1 = red[0];
  __syncthreads();
  red[t] = s2;
  __syncthreads();
  for (int off = 128; off > 0; off >>= 1) {
    if (t < off) red[t] += red[t + off];
    __syncthreads();
  }
  if (t == 0) {
    const float denom = (float)NN * (float)DO;  // mean over [N, 64]
    out[0] = tot1 / denom;
    out[1] = logf(red[0] / denom);
  }
}

}  // namespace

extern "C" void kernel_launch(void* const* d_in, const int* in_sizes, int n_in,
                              void* d_out, int out_size, void* d_ws, size_t ws_size,
                              hipStream_t stream) {
  const float* x    = (const float*)d_in[0];
  const int*   erow = (const int*)d_in[1];
  const int*   ecol = (const int*)d_in[2];
  const float* eval = (const float*)d_in[3];
  const float* W1   = (const float*)d_in[4];
  const float* W2   = (const float*)d_in[5];
  const float* W3   = (const float*)d_in[6];
  float* out = (float*)d_out;

  // workspace carve-out (256B aligned); peak ~104 MB
  char* p = (char*)d_ws;
  auto alloc = [&](size_t bytes) -> void* {
    void* r = (void*)p;
    p += (bytes + 255) & ~(size_t)255;
    return r;
  };
  unsigned short* sup = (unsigned short*)alloc((size_t)NN * DH * 2);  // support1 bf16; reused as support3
  float* h1     = (float*)alloc((size_t)NN * DH * 4);
  float* cval   = (float*)alloc((size_t)NE * 4);
  int*   ccol   = (int*)alloc((size_t)NE * 4);
  int*   rank   = (int*)alloc((size_t)NE * 4);
  int*   rowptr = (int*)alloc((size_t)(NN + 1) * 4);
  int*   cnt    = (int*)alloc((size_t)NN * 4);
  float* hw     = (float*)alloc((size_t)NN * 4);
  float* w2s    = (float*)alloc(DH * 4);
  int*   bsum   = (int*)alloc(SCAN_NB * 4);
  int*   boff   = (int*)alloc(SCAN_NB * 4);
  float* pexp   = (float*)alloc((NN / 16) * 4);
  float* pzmu   = (float*)alloc((NE / 256) * 4);

  hipMemsetAsync(cnt, 0, (size_t)NN * 4, stream);

  // CSR build: 1 atomic per edge total (rank = atomic counter return)
  k_rank<<<NE / 256, 256, 0, stream>>>(erow, cnt, rank);
  k_scan1<<<SCAN_NB, 256, 0, stream>>>(cnt, bsum);
  k_scan2<<<1, 128, 0, stream>>>(bsum, boff, rowptr);
  k_scan3<<<SCAN_NB, 256, 0, stream>>>(cnt, boff, rowptr);
  k_place<<<NE / 256, 256, 0, stream>>>(erow, ecol, eval, rank, rowptr, ccol, cval);

  // layer 1: support1 = x @ W1 (bf16 out)
  k_gemm<128, 128, 16, 8, 8><<<(NN + 127) / 128, 256, 0, stream>>>(x, W1, sup, NN, DI, DH);
  k_w2sum<<<1, 128, 0, stream>>>(W2, w2s);
  // h1 = relu(spmm(support1)); hw = h1 . w2sum   (mu branch folded)
  k_spmm1<<<NN / 8, 256, 0, stream>>>(sup, rowptr, ccol, cval, w2s, h1, hw);

  // layer 2 (logvar only): support3 = h1 @ W3 (bf16 out)
  k_gemm<128, 64, 16, 8, 4><<<(NN + 127) / 128, 256, 0, stream>>>(h1, W3, sup, NN, DH, DO);
  // logvar spmm fused with sum(exp(.)) -> per-block partials
  k_spmm3<<<NN / 16, 256, 0, stream>>>(sup, rowptr, ccol, cval, pexp);

  // z_mu partials: edge-parallel gather-dot (no atomics)
  k_edot<<<NE / 256, 256, 0, stream>>>(ecol, eval, hw, pzmu);
  k_final<<<1, 256, 0, stream>>>(pzmu, NE / 256, pexp, NN / 16, out);
}

// Round 4
// 361.985 us; speedup vs baseline: 1.7246x; 1.2273x over previous
//
#include <hip/hip_runtime.h>
#include <cstdint>
#include <cstddef>

namespace {

constexpr int NN = 100000;   // nodes
constexpr int NE = 1600000;  // edges
constexpr int DI = 256;
constexpr int DH = 128;
constexpr int DO = 64;
constexpr int SCAN_CHUNK = 1024;
constexpr int SCAN_NB = (NN + SCAN_CHUNK - 1) / SCAN_CHUNK;  // 98

using bf16x8 = __attribute__((ext_vector_type(8))) short;  // 8 bf16 = 4 VGPR
using f32x4  = __attribute__((ext_vector_type(4))) float;

__device__ inline float bf2f(unsigned short h) {
  return __uint_as_float((unsigned int)h << 16);
}
__device__ inline unsigned short f2bf(float f) {
  unsigned int u = __float_as_uint(f);
  u += 0x7FFFu + ((u >> 16) & 1u);  // round-to-nearest-even
  return (unsigned short)(u >> 16);
}

// ---------------- CSR build: one atomic per edge total ----------------
__global__ __launch_bounds__(256) void k_rank(const int* __restrict__ erow,
                                              int* __restrict__ cnt,
                                              int* __restrict__ rank) {
  const int e = blockIdx.x * 256 + threadIdx.x;  // grid exact: NE
  rank[e] = atomicAdd(&cnt[erow[e]], 1);
}

__global__ __launch_bounds__(256) void k_scan1(const int* __restrict__ cnt,
                                               int* __restrict__ bsum) {
  __shared__ int red[256];
  const int b = blockIdx.x, t = threadIdx.x;
  const int base = b * SCAN_CHUNK + t * 4;
  int s = 0;
#pragma unroll
  for (int j = 0; j < 4; ++j) {
    const int idx = base + j;
    if (idx < NN) s += cnt[idx];
  }
  red[t] = s;
  __syncthreads();
  for (int off = 128; off > 0; off >>= 1) {
    if (t < off) red[t] += red[t + off];
    __syncthreads();
  }
  if (t == 0) bsum[b] = red[0];
}

__global__ __launch_bounds__(128) void k_scan2(const int* __restrict__ bsum,
                                               int* __restrict__ boff,
                                               int* __restrict__ rowptr) {
  __shared__ int s[128];
  const int t = threadIdx.x;
  const int v = (t < SCAN_NB) ? bsum[t] : 0;
  s[t] = v;
  __syncthreads();
  for (int off = 1; off < 128; off <<= 1) {
    int x = 0;
    if (t >= off) x = s[t - off];
    __syncthreads();
    s[t] += x;
    __syncthreads();
  }
  if (t < SCAN_NB) boff[t] = s[t] - v;   // exclusive block offsets
  if (t == 127) rowptr[NN] = s[127];     // total == NE
}

__global__ __launch_bounds__(256) void k_scan3(const int* __restrict__ cnt,
                                               const int* __restrict__ boff,
                                               int* __restrict__ rowptr) {
  __shared__ int tsum[256];
  const int b = blockIdx.x, t = threadIdx.x;
  const int base = b * SCAN_CHUNK + t * 4;
  int v[4];
#pragma unroll
  for (int j = 0; j < 4; ++j) {
    const int idx = base + j;
    v[j] = (idx < NN) ? cnt[idx] : 0;
  }
  const int pre1 = v[0];
  const int pre2 = pre1 + v[1];
  const int pre3 = pre2 + v[2];
  const int s = pre3 + v[3];
  tsum[t] = s;
  __syncthreads();
  for (int off = 1; off < 256; off <<= 1) {
    int x = 0;
    if (t >= off) x = tsum[t - off];
    __syncthreads();
    tsum[t] += x;
    __syncthreads();
  }
  const int excl = tsum[t] - s + boff[b];
  const int w[4] = {excl, excl + pre1, excl + pre2, excl + pre3};
#pragma unroll
  for (int j = 0; j < 4; ++j) {
    const int idx = base + j;
    if (idx < NN) rowptr[idx] = w[j];
  }
}

// atomic-free placement: pos = rowptr[row] + rank
__global__ __launch_bounds__(256) void k_place(const int* __restrict__ erow,
                                               const int* __restrict__ ecol,
                                               const float* __restrict__ eval,
                                               const int* __restrict__ rank,
                                               const int* __restrict__ rowptr,
                                               int* __restrict__ ccol,
                                               float* __restrict__ cval) {
  const int e = blockIdx.x * 256 + threadIdx.x;  // grid exact: NE
  const int pos = rowptr[erow[e]] + rank[e];
  ccol[pos] = ecol[e];
  cval[pos] = eval[e];
}

// ---------------- prep: W1^T, W3^T (bf16), w2sum ----------------
__global__ __launch_bounds__(256) void k_prep(const float* __restrict__ W1,
                                              const float* __restrict__ W3,
                                              unsigned short* __restrict__ w1t,
                                              unsigned short* __restrict__ w3t) {
  const int i = blockIdx.x * 256 + threadIdx.x;  // grid: (32768+8192)/256 = 160
  if (i < DI * DH) {  // w1t[n][k] = W1[k][n], n<128, k<256
    const int n = i / DI, k = i % DI;
    w1t[i] = f2bf(W1[k * DH + n]);
  } else {
    const int j = i - DI * DH;  // w3t[n][k] = W3[k][n], n<64, k<128
    const int n = j / DH, k = j % DH;
    w3t[j] = f2bf(W3[k * DO + n]);
  }
}

__global__ void k_w2sum(const float* __restrict__ W2, float* __restrict__ w2s) {
  const int k = threadIdx.x;  // 128 threads
  float s = 0.f;
  for (int d = 0; d < DO; ++d) s += W2[k * DO + d];
  w2s[k] = s;
}

// ---------------- MFMA GEMM: C[M][BN] = A[M][K] @ Bt[BN][K]^T (bf16 out) ----
// 4 waves; wave w computes rows [w*32, w*32+32). BN covers the full N.
// LDS tiles XOR-swizzled (byte ^= (row&7)<<4) to kill ds_read_b128 conflicts.
template <int BM, int BN, int BK, bool ABF16>
__global__ __launch_bounds__(256) void k_mfma(const void* __restrict__ Ap,
                                              const unsigned short* __restrict__ Bt,
                                              unsigned short* __restrict__ C,
                                              int M, int K) {
  static_assert(BM == 128 && (BN == 128 || BN == 64) && BK == 64, "tuned shape");
  constexpr int OUTP = BN + 8;  // padded epilogue stride (272B / 144B: 16B-aligned)
  constexpr int STAGE = (BM + BN) * BK * 2;
  constexpr int OUTB = BM * OUTP * 2;
  constexpr int LDSB = STAGE > OUTB ? STAGE : OUTB;
  __shared__ __align__(16) char lds[LDSB];
  char* const as_ = lds;
  char* const bs_ = lds + BM * BK * 2;

  const int tid = threadIdx.x;
  const int wid = tid >> 6;
  const int lane = tid & 63;
  const int l15 = lane & 15;
  const int lg = lane >> 4;  // 0..3
  const int row0 = blockIdx.x * BM;

  f32x4 acc[2][BN / 16];
#pragma unroll
  for (int a = 0; a < 2; ++a)
#pragma unroll
    for (int b = 0; b < BN / 16; ++b) acc[a][b] = (f32x4)0.f;

  for (int k0 = 0; k0 < K; k0 += BK) {
    // ---- stage A tile (convert f32->bf16 if needed) ----
    if constexpr (!ABF16) {
      const float* A = (const float*)Ap;
#pragma unroll
      for (int i = tid; i < BM * (BK / 4); i += 256) {
        const int m = i / (BK / 4), c4 = i % (BK / 4);
        int row = row0 + m;
        if (row >= M) row = M - 1;  // clamp: harmless, stores guarded
        const float4 a = *(const float4*)(&A[(size_t)row * K + k0 + c4 * 4]);
        ushort4 h;
        h.x = f2bf(a.x); h.y = f2bf(a.y); h.z = f2bf(a.z); h.w = f2bf(a.w);
        const int byte = ((m * BK + c4 * 4) * 2) ^ ((m & 7) << 4);
        *(ushort4*)(as_ + byte) = h;
      }
    } else {
      const unsigned short* A = (const unsigned short*)Ap;
#pragma unroll
      for (int i = tid; i < BM * (BK / 8); i += 256) {
        const int m = i / (BK / 8), c8 = i % (BK / 8);
        int row = row0 + m;
        if (row >= M) row = M - 1;
        const float4 a = *(const float4*)(&A[(size_t)row * K + k0 + c8 * 8]);  // 16B = 8 bf16
        const int byte = ((m * BK + c8 * 8) * 2) ^ ((m & 7) << 4);
        *(float4*)(as_ + byte) = a;
      }
    }
    // ---- stage Bt tile (already bf16, rows are K-contiguous) ----
#pragma unroll
    for (int i = tid; i < BN * (BK / 8); i += 256) {
      const int n = i / (BK / 8), c8 = i % (BK / 8);
      const float4 b = *(const float4*)(&Bt[(size_t)n * K + k0 + c8 * 8]);
      const int byte = ((n * BK + c8 * 8) * 2) ^ ((n & 7) << 4);
      *(float4*)(bs_ + byte) = b;
    }
    __syncthreads();
    // ---- MFMA inner loop ----
#pragma unroll
    for (int kk = 0; kk < BK; kk += 32) {
      const int koff = kk + lg * 8;
      const int ra0 = wid * 32 + l15;
      const int ra1 = ra0 + 16;
      const bf16x8 a0 = *(const bf16x8*)(as_ + (((ra0 * BK + koff) * 2) ^ ((ra0 & 7) << 4)));
      const bf16x8 a1 = *(const bf16x8*)(as_ + (((ra1 * BK + koff) * 2) ^ ((ra1 & 7) << 4)));
#pragma unroll
      for (int nf = 0; nf < BN / 16; ++nf) {
        const int n = nf * 16 + l15;
        const bf16x8 b = *(const bf16x8*)(bs_ + (((n * BK + koff) * 2) ^ ((n & 7) << 4)));
        acc[0][nf] = __builtin_amdgcn_mfma_f32_16x16x32_bf16(a0, b, acc[0][nf], 0, 0, 0);
        acc[1][nf] = __builtin_amdgcn_mfma_f32_16x16x32_bf16(a1, b, acc[1][nf], 0, 0, 0);
      }
    }
    __syncthreads();
  }
  // ---- epilogue: transpose through LDS for coalesced bf16 stores ----
  unsigned short* outl = (unsigned short*)lds;
#pragma unroll
  for (int mf = 0; mf < 2; ++mf)
#pragma unroll
    for (int nf = 0; nf < BN / 16; ++nf)
#pragma unroll
      for (int r = 0; r < 4; ++r) {
        const int row = wid * 32 + mf * 16 + lg * 4 + r;  // D: row=(lane>>4)*4+r
        const int col = nf * 16 + l15;                    //    col=lane&15
        outl[row * OUTP + col] = f2bf(acc[mf][nf][r]);
      }
  __syncthreads();
#pragma unroll
  for (int i = tid; i < BM * (BN / 8); i += 256) {
    const int m = i / (BN / 8), c8 = i % (BN / 8);
    const int row = row0 + m;
    if (row < M)
      *(float4*)(&C[(size_t)row * BN + c8 * 8]) = *(const float4*)(&outl[m * OUTP + c8 * 8]);
  }
}

// ---------------- SPMM1 (bf16 gather) + relu + hw; h1 out bf16 ----------------
__global__ __launch_bounds__(256) void k_spmm1(const unsigned short* __restrict__ sup1,
                                               const int* __restrict__ rowptr,
                                               const int* __restrict__ ccol,
                                               const float* __restrict__ cval,
                                               const float* __restrict__ w2s,
                                               unsigned short* __restrict__ h1,
                                               float* __restrict__ hw) {
  const int r = blockIdx.x * 8 + (threadIdx.x >> 5);  // grid exact: NN/8
  const int lane = threadIdx.x & 31;                  // 32 lanes x 4ch = 128 ch
  const int e0 = rowptr[r];
  const int e1 = rowptr[r + 1];
  const ushort4* s4 = reinterpret_cast<const ushort4*>(sup1);  // 8B = 4 bf16
  float ax = 0.f, ay = 0.f, az = 0.f, aw = 0.f;
  for (int e = e0; e < e1; ++e) {
    const int c = ccol[e];
    const float v = cval[e];
    const ushort4 sv = s4[(size_t)c * 32 + lane];
    ax = fmaf(v, bf2f(sv.x), ax); ay = fmaf(v, bf2f(sv.y), ay);
    az = fmaf(v, bf2f(sv.z), az); aw = fmaf(v, bf2f(sv.w), aw);
  }
  ax = fmaxf(ax, 0.f); ay = fmaxf(ay, 0.f);
  az = fmaxf(az, 0.f); aw = fmaxf(aw, 0.f);
  ushort4 o;
  o.x = f2bf(ax); o.y = f2bf(ay); o.z = f2bf(az); o.w = f2bf(aw);
  reinterpret_cast<ushort4*>(h1)[(size_t)r * 32 + lane] = o;
  // hw[r] = relu_row . w2sum  (feeds the folded z_mu)
  const float4 w = reinterpret_cast<const float4*>(w2s)[lane];
  float p = ax * w.x + ay * w.y + az * w.z + aw * w.w;
  for (int off = 16; off > 0; off >>= 1) p += __shfl_down(p, off, 32);
  if (lane == 0) hw[r] = p;
}

// ---------------- SPMM3 (bf16 gather) + exp + reduce ----------------
__global__ __launch_bounds__(256) void k_spmm3(const unsigned short* __restrict__ sup3,
                                               const int* __restrict__ rowptr,
                                               const int* __restrict__ ccol,
                                               const float* __restrict__ cval,
                                               float* __restrict__ pexp) {
  const int r = blockIdx.x * 16 + (threadIdx.x >> 4);  // grid exact: NN/16
  const int lane = threadIdx.x & 15;                   // 16 lanes x 4ch = 64 ch
  const int e0 = rowptr[r];
  const int e1 = rowptr[r + 1];
  const ushort4* s4 = reinterpret_cast<const ushort4*>(sup3);
  float ax = 0.f, ay = 0.f, az = 0.f, aw = 0.f;
  for (int e = e0; e < e1; ++e) {
    const int c = ccol[e];
    const float v = cval[e];
    const ushort4 sv = s4[(size_t)c * 16 + lane];
    ax = fmaf(v, bf2f(sv.x), ax); ay = fmaf(v, bf2f(sv.y), ay);
    az = fmaf(v, bf2f(sv.z), az); aw = fmaf(v, bf2f(sv.w), aw);
  }
  float p = expf(ax) + expf(ay) + expf(az) + expf(aw);
  for (int off = 8; off > 0; off >>= 1) p += __shfl_down(p, off, 16);
  __shared__ float part[16];
  if (lane == 0) part[threadIdx.x >> 4] = p;
  __syncthreads();
  if (threadIdx.x == 0) {
    float s = 0.f;
#pragma unroll
    for (int i = 0; i < 16; ++i) s += part[i];
    pexp[blockIdx.x] = s;
  }
}

// ---------------- z_mu partials: sum_e val_e * hw[col_e] ----------------
__global__ __launch_bounds__(256) void k_edot(const int* __restrict__ ecol,
                                              const float* __restrict__ eval,
                                              const float* __restrict__ hw,
                                              float* __restrict__ pzmu) {
  __shared__ float red[256];
  const int i = blockIdx.x * 256 + threadIdx.x;  // grid exact: NE/256
  red[threadIdx.x] = eval[i] * hw[ecol[i]];
  __syncthreads();
  for (int off = 128; off > 0; off >>= 1) {
    if (threadIdx.x < off) red[threadIdx.x] += red[threadIdx.x + off];
    __syncthreads();
  }
  if (threadIdx.x == 0) pzmu[blockIdx.x] = red[0];
}

// ---------------- finalize ----------------
__global__ __launch_bounds__(256) void k_final(const float* __restrict__ pzmu, int nz,
                                               const float* __restrict__ pexp, int ne,
                                               float* __restrict__ out) {
  __shared__ float red[256];
  const int t = threadIdx.x;
  float s1 = 0.f, s2 = 0.f;
  for (int i = t; i < nz; i += 256) s1 += pzmu[i];
  for (int i = t; i < ne; i += 256) s2 += pexp[i];
  red[t] = s1;
  __syncthreads();
  for (int off = 128; off > 0; off >>= 1) {
    if (t < off) red[t] += red[t + off];
    __syncthreads();
  }
  const float tot1 = red[0];
  __syncthreads();
  red[t] = s2;
  __syncthreads();
  for (int off = 128; off > 0; off >>= 1) {
    if (t < off) red[t] += red[t + off];
    __syncthreads();
  }
  if (t == 0) {
    const float denom = (float)NN * (float)DO;  // mean over [N, 64]
    out[0] = tot1 / denom;
    out[1] = logf(red[0] / denom);
  }
}

}  // namespace

extern "C" void kernel_launch(void* const* d_in, const int* in_sizes, int n_in,
                              void* d_out, int out_size, void* d_ws, size_t ws_size,
                              hipStream_t stream) {
  const float* x    = (const float*)d_in[0];
  const int*   erow = (const int*)d_in[1];
  const int*   ecol = (const int*)d_in[2];
  const float* eval = (const float*)d_in[3];
  const float* W1   = (const float*)d_in[4];
  const float* W2   = (const float*)d_in[5];
  const float* W3   = (const float*)d_in[6];
  float* out = (float*)d_out;

  // workspace carve-out (256B aligned); peak ~80 MB
  char* p = (char*)d_ws;
  auto alloc = [&](size_t bytes) -> void* {
    void* r = (void*)p;
    p += (bytes + 255) & ~(size_t)255;
    return r;
  };
  unsigned short* sup = (unsigned short*)alloc((size_t)NN * DH * 2);  // support1; reused as support3
  unsigned short* h1  = (unsigned short*)alloc((size_t)NN * DH * 2);  // h1 bf16
  float* cval   = (float*)alloc((size_t)NE * 4);
  int*   ccol   = (int*)alloc((size_t)NE * 4);
  int*   rank   = (int*)alloc((size_t)NE * 4);
  int*   rowptr = (int*)alloc((size_t)(NN + 1) * 4);
  int*   cnt    = (int*)alloc((size_t)NN * 4);
  float* hw     = (float*)alloc((size_t)NN * 4);
  float* w2s    = (float*)alloc(DH * 4);
  unsigned short* w1t = (unsigned short*)alloc((size_t)DH * DI * 2);  // W1^T bf16 [128][256]
  unsigned short* w3t = (unsigned short*)alloc((size_t)DO * DH * 2);  // W3^T bf16 [64][128]
  int*   bsum   = (int*)alloc(SCAN_NB * 4);
  int*   boff   = (int*)alloc(SCAN_NB * 4);
  float* pexp   = (float*)alloc((NN / 16) * 4);
  float* pzmu   = (float*)alloc((NE / 256) * 4);

  hipMemsetAsync(cnt, 0, (size_t)NN * 4, stream);

  // CSR build: 1 atomic per edge total (rank = atomic counter return)
  k_rank<<<NE / 256, 256, 0, stream>>>(erow, cnt, rank);
  k_scan1<<<SCAN_NB, 256, 0, stream>>>(cnt, bsum);
  k_scan2<<<1, 128, 0, stream>>>(bsum, boff, rowptr);
  k_scan3<<<SCAN_NB, 256, 0, stream>>>(cnt, boff, rowptr);
  k_place<<<NE / 256, 256, 0, stream>>>(erow, ecol, eval, rank, rowptr, ccol, cval);

  // weight prep (transposed bf16 copies) + w2sum
  k_prep<<<(DI * DH + DH * DO) / 256, 256, 0, stream>>>(W1, W3, w1t, w3t);
  k_w2sum<<<1, 128, 0, stream>>>(W2, w2s);

  // layer 1: support1 = x @ W1 (MFMA bf16)
  k_mfma<128, 128, 64, false><<<(NN + 127) / 128, 256, 0, stream>>>(x, w1t, sup, NN, DI);
  // h1 = relu(spmm(support1)) [bf16]; hw = h1 . w2sum   (mu branch folded)
  k_spmm1<<<NN / 8, 256, 0, stream>>>(sup, rowptr, ccol, cval, w2s, h1, hw);

  // layer 2 (logvar only): support3 = h1 @ W3 (MFMA bf16)
  k_mfma<128, 64, 64, true><<<(NN + 127) / 128, 256, 0, stream>>>(h1, w3t, sup, NN, DH);
  // logvar spmm fused with sum(exp(.)) -> per-block partials
  k_spmm3<<<NN / 16, 256, 0, stream>>>(sup, rowptr, ccol, cval, pexp);

  // z_mu partials: edge-parallel gather-dot (no atomics)
  k_edot<<<NE / 256, 256, 0, stream>>>(ecol, eval, hw, pzmu);
  k_final<<<1, 256, 0, stream>>>(pzmu, NE / 256, pexp, NN / 16, out);
}

// Round 5
// 268.553 us; speedup vs baseline: 2.3246x; 1.3479x over previous
//
#include <hip/hip_runtime.h>
#include <cstdint>
#include <cstddef>

namespace {

constexpr int NN = 100000;   // nodes
constexpr int NE = 1600000;  // edges
constexpr int DI = 256;
constexpr int DH = 128;
constexpr int DO = 64;
constexpr int SCAN_CHUNK = 1024;
constexpr int SCAN_NB = (NN + SCAN_CHUNK - 1) / SCAN_CHUNK;  // 98
constexpr int SP3_NB = NN / 32;   // 3125 spmm3 blocks
constexpr int EDOT_NB = NE / 256; // 6250 edot blocks

using bf16x8 = __attribute__((ext_vector_type(8))) short;  // 8 bf16 = 4 VGPR
using f32x4  = __attribute__((ext_vector_type(4))) float;

__device__ inline float bf2f(unsigned short h) {
  return __uint_as_float((unsigned int)h << 16);
}
__device__ inline unsigned short f2bf(float f) {
  unsigned int u = __float_as_uint(f);
  u += 0x7FFFu + ((u >> 16) & 1u);  // round-to-nearest-even
  return (unsigned short)(u >> 16);
}
__device__ inline float bflo(unsigned int u) { return __uint_as_float(u << 16); }
__device__ inline float bfhi(unsigned int u) { return __uint_as_float(u & 0xffff0000u); }

// fma 8 bf16 (packed in uint4) * v into acc[8]
__device__ inline void fma8(float* acc, const uint4 g, const float v) {
  acc[0] = fmaf(v, bflo(g.x), acc[0]); acc[1] = fmaf(v, bfhi(g.x), acc[1]);
  acc[2] = fmaf(v, bflo(g.y), acc[2]); acc[3] = fmaf(v, bfhi(g.y), acc[3]);
  acc[4] = fmaf(v, bflo(g.z), acc[4]); acc[5] = fmaf(v, bfhi(g.z), acc[5]);
  acc[6] = fmaf(v, bflo(g.w), acc[6]); acc[7] = fmaf(v, bfhi(g.w), acc[7]);
}

// ---------------- CSR build: one atomic per edge total ----------------
__global__ __launch_bounds__(256) void k_rank(const int* __restrict__ erow,
                                              int* __restrict__ cnt,
                                              int* __restrict__ rank) {
  const int e = blockIdx.x * 256 + threadIdx.x;  // grid exact: NE
  rank[e] = atomicAdd(&cnt[erow[e]], 1);
}

__global__ __launch_bounds__(256) void k_scan1(const int* __restrict__ cnt,
                                               int* __restrict__ bsum) {
  __shared__ int red[256];
  const int b = blockIdx.x, t = threadIdx.x;
  const int base = b * SCAN_CHUNK + t * 4;
  int s = 0;
#pragma unroll
  for (int j = 0; j < 4; ++j) {
    const int idx = base + j;
    if (idx < NN) s += cnt[idx];
  }
  red[t] = s;
  __syncthreads();
  for (int off = 128; off > 0; off >>= 1) {
    if (t < off) red[t] += red[t + off];
    __syncthreads();
  }
  if (t == 0) bsum[b] = red[0];
}

__global__ __launch_bounds__(128) void k_scan2(const int* __restrict__ bsum,
                                               int* __restrict__ boff,
                                               int* __restrict__ rowptr) {
  __shared__ int s[128];
  const int t = threadIdx.x;
  const int v = (t < SCAN_NB) ? bsum[t] : 0;
  s[t] = v;
  __syncthreads();
  for (int off = 1; off < 128; off <<= 1) {
    int x = 0;
    if (t >= off) x = s[t - off];
    __syncthreads();
    s[t] += x;
    __syncthreads();
  }
  if (t < SCAN_NB) boff[t] = s[t] - v;   // exclusive block offsets
  if (t == 127) rowptr[NN] = s[127];     // total == NE
}

__global__ __launch_bounds__(256) void k_scan3(const int* __restrict__ cnt,
                                               const int* __restrict__ boff,
                                               int* __restrict__ rowptr) {
  __shared__ int tsum[256];
  const int b = blockIdx.x, t = threadIdx.x;
  const int base = b * SCAN_CHUNK + t * 4;
  int v[4];
#pragma unroll
  for (int j = 0; j < 4; ++j) {
    const int idx = base + j;
    v[j] = (idx < NN) ? cnt[idx] : 0;
  }
  const int pre1 = v[0];
  const int pre2 = pre1 + v[1];
  const int pre3 = pre2 + v[2];
  const int s = pre3 + v[3];
  tsum[t] = s;
  __syncthreads();
  for (int off = 1; off < 256; off <<= 1) {
    int x = 0;
    if (t >= off) x = tsum[t - off];
    __syncthreads();
    tsum[t] += x;
    __syncthreads();
  }
  const int excl = tsum[t] - s + boff[b];
  const int w[4] = {excl, excl + pre1, excl + pre2, excl + pre3};
#pragma unroll
  for (int j = 0; j < 4; ++j) {
    const int idx = base + j;
    if (idx < NN) rowptr[idx] = w[j];
  }
}

// atomic-free placement: pos = rowptr[row] + rank; packed (col, valbits)
__global__ __launch_bounds__(256) void k_place(const int* __restrict__ erow,
                                               const int* __restrict__ ecol,
                                               const float* __restrict__ eval,
                                               const int* __restrict__ rank,
                                               const int* __restrict__ rowptr,
                                               int2* __restrict__ cpk) {
  const int e = blockIdx.x * 256 + threadIdx.x;  // grid exact: NE
  const int pos = rowptr[erow[e]] + rank[e];
  cpk[pos] = make_int2(ecol[e], __float_as_int(eval[e]));
}

// ---------------- prep: W1^T, W3^T (bf16), w2sum ----------------
__global__ __launch_bounds__(256) void k_prep(const float* __restrict__ W1,
                                              const float* __restrict__ W3,
                                              unsigned short* __restrict__ w1t,
                                              unsigned short* __restrict__ w3t) {
  const int i = blockIdx.x * 256 + threadIdx.x;  // grid: (32768+8192)/256 = 160
  if (i < DI * DH) {  // w1t[n][k] = W1[k][n], n<128, k<256
    const int n = i / DI, k = i % DI;
    w1t[i] = f2bf(W1[k * DH + n]);
  } else {
    const int j = i - DI * DH;  // w3t[n][k] = W3[k][n], n<64, k<128
    const int n = j / DH, k = j % DH;
    w3t[j] = f2bf(W3[k * DO + n]);
  }
}

__global__ void k_w2sum(const float* __restrict__ W2, float* __restrict__ w2s) {
  const int k = threadIdx.x;  // 128 threads
  float s = 0.f;
  for (int d = 0; d < DO; ++d) s += W2[k * DO + d];
  w2s[k] = s;
}

// ---------------- MFMA GEMM: C[M][BN] = A[M][K] @ Bt[BN][K]^T (bf16 out) ----
template <int BM, int BN, int BK, bool ABF16>
__global__ __launch_bounds__(256) void k_mfma(const void* __restrict__ Ap,
                                              const unsigned short* __restrict__ Bt,
                                              unsigned short* __restrict__ C,
                                              int M, int K) {
  static_assert(BM == 128 && (BN == 128 || BN == 64) && BK == 64, "tuned shape");
  constexpr int OUTP = BN + 8;  // padded epilogue stride
  constexpr int STAGE = (BM + BN) * BK * 2;
  constexpr int OUTB = BM * OUTP * 2;
  constexpr int LDSB = STAGE > OUTB ? STAGE : OUTB;
  __shared__ __align__(16) char lds[LDSB];
  char* const as_ = lds;
  char* const bs_ = lds + BM * BK * 2;

  const int tid = threadIdx.x;
  const int wid = tid >> 6;
  const int lane = tid & 63;
  const int l15 = lane & 15;
  const int lg = lane >> 4;  // 0..3
  const int row0 = blockIdx.x * BM;

  f32x4 acc[2][BN / 16];
#pragma unroll
  for (int a = 0; a < 2; ++a)
#pragma unroll
    for (int b = 0; b < BN / 16; ++b) acc[a][b] = (f32x4)0.f;

  for (int k0 = 0; k0 < K; k0 += BK) {
    if constexpr (!ABF16) {
      const float* A = (const float*)Ap;
#pragma unroll
      for (int i = tid; i < BM * (BK / 4); i += 256) {
        const int m = i / (BK / 4), c4 = i % (BK / 4);
        int row = row0 + m;
        if (row >= M) row = M - 1;  // clamp: harmless, stores guarded
        const float4 a = *(const float4*)(&A[(size_t)row * K + k0 + c4 * 4]);
        ushort4 h;
        h.x = f2bf(a.x); h.y = f2bf(a.y); h.z = f2bf(a.z); h.w = f2bf(a.w);
        const int byte = ((m * BK + c4 * 4) * 2) ^ ((m & 7) << 4);
        *(ushort4*)(as_ + byte) = h;
      }
    } else {
      const unsigned short* A = (const unsigned short*)Ap;
#pragma unroll
      for (int i = tid; i < BM * (BK / 8); i += 256) {
        const int m = i / (BK / 8), c8 = i % (BK / 8);
        int row = row0 + m;
        if (row >= M) row = M - 1;
        const float4 a = *(const float4*)(&A[(size_t)row * K + k0 + c8 * 8]);
        const int byte = ((m * BK + c8 * 8) * 2) ^ ((m & 7) << 4);
        *(float4*)(as_ + byte) = a;
      }
    }
#pragma unroll
    for (int i = tid; i < BN * (BK / 8); i += 256) {
      const int n = i / (BK / 8), c8 = i % (BK / 8);
      const float4 b = *(const float4*)(&Bt[(size_t)n * K + k0 + c8 * 8]);
      const int byte = ((n * BK + c8 * 8) * 2) ^ ((n & 7) << 4);
      *(float4*)(bs_ + byte) = b;
    }
    __syncthreads();
#pragma unroll
    for (int kk = 0; kk < BK; kk += 32) {
      const int koff = kk + lg * 8;
      const int ra0 = wid * 32 + l15;
      const int ra1 = ra0 + 16;
      const bf16x8 a0 = *(const bf16x8*)(as_ + (((ra0 * BK + koff) * 2) ^ ((ra0 & 7) << 4)));
      const bf16x8 a1 = *(const bf16x8*)(as_ + (((ra1 * BK + koff) * 2) ^ ((ra1 & 7) << 4)));
#pragma unroll
      for (int nf = 0; nf < BN / 16; ++nf) {
        const int n = nf * 16 + l15;
        const bf16x8 b = *(const bf16x8*)(bs_ + (((n * BK + koff) * 2) ^ ((n & 7) << 4)));
        acc[0][nf] = __builtin_amdgcn_mfma_f32_16x16x32_bf16(a0, b, acc[0][nf], 0, 0, 0);
        acc[1][nf] = __builtin_amdgcn_mfma_f32_16x16x32_bf16(a1, b, acc[1][nf], 0, 0, 0);
      }
    }
    __syncthreads();
  }
  // epilogue: transpose through LDS for coalesced bf16 stores
  unsigned short* outl = (unsigned short*)lds;
#pragma unroll
  for (int mf = 0; mf < 2; ++mf)
#pragma unroll
    for (int nf = 0; nf < BN / 16; ++nf)
#pragma unroll
      for (int r = 0; r < 4; ++r) {
        const int row = wid * 32 + mf * 16 + lg * 4 + r;  // D: row=(lane>>4)*4+r
        const int col = nf * 16 + l15;                    //    col=lane&15
        outl[row * OUTP + col] = f2bf(acc[mf][nf][r]);
      }
  __syncthreads();
#pragma unroll
  for (int i = tid; i < BM * (BN / 8); i += 256) {
    const int m = i / (BN / 8), c8 = i % (BN / 8);
    const int row = row0 + m;
    if (row < M)
      *(float4*)(&C[(size_t)row * BN + c8 * 8]) = *(const float4*)(&outl[m * OUTP + c8 * 8]);
  }
}

// ---------------- SPMM1: 16 lanes/row, unroll x2, packed edge stream ------
__global__ __launch_bounds__(256) void k_spmm1(const unsigned short* __restrict__ sup1,
                                               const int* __restrict__ rowptr,
                                               const int2* __restrict__ cpk,
                                               const float* __restrict__ w2s,
                                               unsigned short* __restrict__ h1,
                                               float* __restrict__ hw) {
  const int tid = threadIdx.x;
  const int lane = tid & 15;                       // 16 lanes x 8 bf16 = 128 ch
  const int r = blockIdx.x * 16 + (tid >> 4);      // grid exact: NN/16
  const int e0 = rowptr[r];
  const int e1 = rowptr[r + 1];
  const uint4* s8 = reinterpret_cast<const uint4*>(sup1);  // 16B = 8 bf16
  float a0[8] = {0.f, 0.f, 0.f, 0.f, 0.f, 0.f, 0.f, 0.f};
  float a1[8] = {0.f, 0.f, 0.f, 0.f, 0.f, 0.f, 0.f, 0.f};
  int e = e0;
  for (; e + 2 <= e1; e += 2) {
    const int2 p0 = cpk[e];
    const int2 p1 = cpk[e + 1];
    const uint4 g0 = s8[(size_t)p0.x * 16 + lane];
    const uint4 g1 = s8[(size_t)p1.x * 16 + lane];
    fma8(a0, g0, __int_as_float(p0.y));
    fma8(a1, g1, __int_as_float(p1.y));
  }
  if (e < e1) {
    const int2 p0 = cpk[e];
    const uint4 g0 = s8[(size_t)p0.x * 16 + lane];
    fma8(a0, g0, __int_as_float(p0.y));
  }
  float acc[8];
#pragma unroll
  for (int j = 0; j < 8; ++j) acc[j] = fmaxf(a0[j] + a1[j], 0.f);
  uint4 o;
  o.x = (unsigned)f2bf(acc[0]) | ((unsigned)f2bf(acc[1]) << 16);
  o.y = (unsigned)f2bf(acc[2]) | ((unsigned)f2bf(acc[3]) << 16);
  o.z = (unsigned)f2bf(acc[4]) | ((unsigned)f2bf(acc[5]) << 16);
  o.w = (unsigned)f2bf(acc[6]) | ((unsigned)f2bf(acc[7]) << 16);
  reinterpret_cast<uint4*>(h1)[(size_t)r * 16 + lane] = o;
  // hw[r] = relu_row . w2sum  (feeds the folded z_mu)
  const float4 wlo = reinterpret_cast<const float4*>(w2s)[lane * 2];
  const float4 whi = reinterpret_cast<const float4*>(w2s)[lane * 2 + 1];
  float p = acc[0] * wlo.x + acc[1] * wlo.y + acc[2] * wlo.z + acc[3] * wlo.w +
            acc[4] * whi.x + acc[5] * whi.y + acc[6] * whi.z + acc[7] * whi.w;
#pragma unroll
  for (int off = 8; off > 0; off >>= 1) p += __shfl_down(p, off, 16);
  if (lane == 0) hw[r] = p;
}

// ---------------- fused SPMM3(+exp reduce) and EDOT (block-range split) ----
__global__ __launch_bounds__(256) void k_spmm3_edot(
    const unsigned short* __restrict__ sup3,
    const int* __restrict__ rowptr,
    const int2* __restrict__ cpk,
    const int* __restrict__ ecol,
    const float* __restrict__ eval,
    const float* __restrict__ hw,
    float* __restrict__ pexp,
    float* __restrict__ pzmu) {
  if (blockIdx.x < SP3_NB) {
    // spmm3: 8 lanes/row x 8 bf16 = 64 ch; 32 rows/block; unroll x2
    const int tid = threadIdx.x;
    const int lane = tid & 7;
    const int r = blockIdx.x * 32 + (tid >> 3);
    const int e0 = rowptr[r];
    const int e1 = rowptr[r + 1];
    const uint4* s8 = reinterpret_cast<const uint4*>(sup3);
    float a0[8] = {0.f, 0.f, 0.f, 0.f, 0.f, 0.f, 0.f, 0.f};
    float a1[8] = {0.f, 0.f, 0.f, 0.f, 0.f, 0.f, 0.f, 0.f};
    int e = e0;
    for (; e + 2 <= e1; e += 2) {
      const int2 p0 = cpk[e];
      const int2 p1 = cpk[e + 1];
      const uint4 g0 = s8[(size_t)p0.x * 8 + lane];
      const uint4 g1 = s8[(size_t)p1.x * 8 + lane];
      fma8(a0, g0, __int_as_float(p0.y));
      fma8(a1, g1, __int_as_float(p1.y));
    }
    if (e < e1) {
      const int2 p0 = cpk[e];
      const uint4 g0 = s8[(size_t)p0.x * 8 + lane];
      fma8(a0, g0, __int_as_float(p0.y));
    }
    float p = 0.f;
#pragma unroll
    for (int j = 0; j < 8; ++j) p += expf(a0[j] + a1[j]);
#pragma unroll
    for (int off = 4; off > 0; off >>= 1) p += __shfl_down(p, off, 8);
    __shared__ float part[32];
    if (lane == 0) part[tid >> 3] = p;
    __syncthreads();
    if (tid == 0) {
      float s = 0.f;
#pragma unroll
      for (int i = 0; i < 32; ++i) s += part[i];
      pexp[blockIdx.x] = s;
    }
  } else {
    // edot: z_mu partials, sum_e val_e * hw[col_e]
    const int b = blockIdx.x - SP3_NB;
    const int i = b * 256 + threadIdx.x;  // exact: EDOT_NB*256 == NE
    __shared__ float red[256];
    red[threadIdx.x] = eval[i] * hw[ecol[i]];
    __syncthreads();
    for (int off = 128; off > 0; off >>= 1) {
      if (threadIdx.x < off) red[threadIdx.x] += red[threadIdx.x + off];
      __syncthreads();
    }
    if (threadIdx.x == 0) pzmu[b] = red[0];
  }
}

// ---------------- finalize ----------------
__global__ __launch_bounds__(256) void k_final(const float* __restrict__ pzmu, int nz,
                                               const float* __restrict__ pexp, int ne,
                                               float* __restrict__ out) {
  __shared__ float red[256];
  const int t = threadIdx.x;
  float s1 = 0.f, s2 = 0.f;
  for (int i = t; i < nz; i += 256) s1 += pzmu[i];
  for (int i = t; i < ne; i += 256) s2 += pexp[i];
  red[t] = s1;
  __syncthreads();
  for (int off = 128; off > 0; off >>= 1) {
    if (t < off) red[t] += red[t + off];
    __syncthreads();
  }
  const float tot1 = red[0];
  __syncthreads();
  red[t] = s2;
  __syncthreads();
  for (int off = 128; off > 0; off >>= 1) {
    if (t < off) red[t] += red[t + off];
    __syncthreads();
  }
  if (t == 0) {
    const float denom = (float)NN * (float)DO;  // mean over [N, 64]
    out[0] = tot1 / denom;
    out[1] = logf(red[0] / denom);
  }
}

}  // namespace

extern "C" void kernel_launch(void* const* d_in, const int* in_sizes, int n_in,
                              void* d_out, int out_size, void* d_ws, size_t ws_size,
                              hipStream_t stream) {
  const float* x    = (const float*)d_in[0];
  const int*   erow = (const int*)d_in[1];
  const int*   ecol = (const int*)d_in[2];
  const float* eval = (const float*)d_in[3];
  const float* W1   = (const float*)d_in[4];
  const float* W2   = (const float*)d_in[5];
  const float* W3   = (const float*)d_in[6];
  float* out = (float*)d_out;

  // workspace carve-out (256B aligned); peak ~80 MB
  char* p = (char*)d_ws;
  auto alloc = [&](size_t bytes) -> void* {
    void* r = (void*)p;
    p += (bytes + 255) & ~(size_t)255;
    return r;
  };
  unsigned short* sup = (unsigned short*)alloc((size_t)NN * DH * 2);  // support1; reused as support3
  unsigned short* h1  = (unsigned short*)alloc((size_t)NN * DH * 2);  // h1 bf16
  int2*  cpk   = (int2*)alloc((size_t)NE * 8);   // packed (col, valbits)
  int*   rank   = (int*)alloc((size_t)NE * 4);
  int*   rowptr = (int*)alloc((size_t)(NN + 1) * 4);
  int*   cnt    = (int*)alloc((size_t)NN * 4);
  float* hw     = (float*)alloc((size_t)NN * 4);
  float* w2s    = (float*)alloc(DH * 4);
  unsigned short* w1t = (unsigned short*)alloc((size_t)DH * DI * 2);  // W1^T bf16 [128][256]
  unsigned short* w3t = (unsigned short*)alloc((size_t)DO * DH * 2);  // W3^T bf16 [64][128]
  int*   bsum   = (int*)alloc(SCAN_NB * 4);
  int*   boff   = (int*)alloc(SCAN_NB * 4);
  float* pexp   = (float*)alloc(SP3_NB * 4);
  float* pzmu   = (float*)alloc(EDOT_NB * 4);

  hipMemsetAsync(cnt, 0, (size_t)NN * 4, stream);

  // CSR build: 1 atomic per edge total (rank = atomic counter return)
  k_rank<<<NE / 256, 256, 0, stream>>>(erow, cnt, rank);
  k_scan1<<<SCAN_NB, 256, 0, stream>>>(cnt, bsum);
  k_scan2<<<1, 128, 0, stream>>>(bsum, boff, rowptr);
  k_scan3<<<SCAN_NB, 256, 0, stream>>>(cnt, boff, rowptr);
  k_place<<<NE / 256, 256, 0, stream>>>(erow, ecol, eval, rank, rowptr, cpk);

  // weight prep (transposed bf16 copies) + w2sum
  k_prep<<<(DI * DH + DH * DO) / 256, 256, 0, stream>>>(W1, W3, w1t, w3t);
  k_w2sum<<<1, 128, 0, stream>>>(W2, w2s);

  // layer 1: support1 = x @ W1 (MFMA bf16)
  k_mfma<128, 128, 64, false><<<(NN + 127) / 128, 256, 0, stream>>>(x, w1t, sup, NN, DI);
  // h1 = relu(spmm(support1)) [bf16]; hw = h1 . w2sum   (mu branch folded)
  k_spmm1<<<NN / 16, 256, 0, stream>>>(sup, rowptr, cpk, w2s, h1, hw);

  // layer 2 (logvar only): support3 = h1 @ W3 (MFMA bf16)
  k_mfma<128, 64, 64, true><<<(NN + 127) / 128, 256, 0, stream>>>(h1, w3t, sup, NN, DH);
  // fused: logvar spmm + sum(exp) partials, and z_mu edge-dot partials
  k_spmm3_edot<<<SP3_NB + EDOT_NB, 256, 0, stream>>>(sup, rowptr, cpk, ecol, eval, hw,
                                                     pexp, pzmu);

  k_final<<<1, 256, 0, stream>>>(pzmu, EDOT_NB, pexp, SP3_NB, out);
}

// Round 6
// 261.995 us; speedup vs baseline: 2.3828x; 1.0250x over previous
//
#include <hip/hip_runtime.h>
#include <cstdint>
#include <cstddef>

namespace {

constexpr int NN = 100000;   // nodes
constexpr int NE = 1600000;  // edges
constexpr int DI = 256;
constexpr int DH = 128;
constexpr int DO = 64;
constexpr int SCAN_CHUNK = 1024;
constexpr int SCAN_NB = (NN + SCAN_CHUNK - 1) / SCAN_CHUNK;  // 98
constexpr int RANK_NB = NE / 256;   // 6250
constexpr int EDOT_NB = NE / 256;   // 6250
constexpr int SP3_NB = NN / 32;     // 3125
constexpr int G1_NB = (NN + 127) / 128;  // 782 gemm blocks
constexpr int PREP_NB = (DI * DH + DH * DO) / 256;  // 160

using bf16x8 = __attribute__((ext_vector_type(8))) short;  // 8 bf16 = 4 VGPR
using f32x4  = __attribute__((ext_vector_type(4))) float;

__device__ inline float bf2f(unsigned short h) {
  return __uint_as_float((unsigned int)h << 16);
}
__device__ inline unsigned short f2bf(float f) {
  unsigned int u = __float_as_uint(f);
  u += 0x7FFFu + ((u >> 16) & 1u);  // round-to-nearest-even
  return (unsigned short)(u >> 16);
}
__device__ inline float bflo(unsigned int u) { return __uint_as_float(u << 16); }
__device__ inline float bfhi(unsigned int u) { return __uint_as_float(u & 0xffff0000u); }

__device__ inline void fma8(float* acc, const uint4 g, const float v) {
  acc[0] = fmaf(v, bflo(g.x), acc[0]); acc[1] = fmaf(v, bfhi(g.x), acc[1]);
  acc[2] = fmaf(v, bflo(g.y), acc[2]); acc[3] = fmaf(v, bfhi(g.y), acc[3]);
  acc[4] = fmaf(v, bflo(g.z), acc[4]); acc[5] = fmaf(v, bfhi(g.z), acc[5]);
  acc[6] = fmaf(v, bflo(g.w), acc[6]); acc[7] = fmaf(v, bfhi(g.w), acc[7]);
}

// ---- MFMA GEMM block body: C[M][BN] = A[M][K] @ Bt[BN][K]^T (bf16 out) ----
// Register-prefetched (fetch tile t+1 before MFMA of tile t, T14 pattern).
// LDS XOR-swizzled (byte ^= (row&7)<<4) against ds_read_b128 conflicts.
template <int BM, int BN, int BK, bool ABF16>
__device__ __forceinline__ void gemm_block(const void* __restrict__ Ap,
                                           const unsigned short* __restrict__ Bt,
                                           unsigned short* __restrict__ C,
                                           int M, int K, int bx) {
  constexpr int OUTP = BN + 8;
  constexpr int STAGE = (BM + BN) * BK * 2;
  constexpr int OUTB = BM * OUTP * 2;
  constexpr int LDSB = STAGE > OUTB ? STAGE : OUTB;
  __shared__ __align__(16) char lds[LDSB];
  char* const as_ = lds;
  char* const bs_ = lds + BM * BK * 2;

  const int tid = threadIdx.x;
  const int wid = tid >> 6;
  const int lane = tid & 63;
  const int l15 = lane & 15;
  const int lg = lane >> 4;  // 0..3
  const int row0 = bx * BM;

  constexpr int NA = ABF16 ? (BM * BK / 8) / 256 : (BM * BK / 4) / 256;
  constexpr int NB = (BN * BK / 8) / 256;
  float4 ra[NA], rb[NB];

  auto fetch = [&](int k0) {
    if constexpr (!ABF16) {
      const float* A = (const float*)Ap;
#pragma unroll
      for (int j = 0; j < NA; ++j) {
        const int i = tid + j * 256;
        const int m = i / (BK / 4), c4 = i % (BK / 4);
        int row = row0 + m;
        if (row >= M) row = M - 1;  // clamp: harmless, stores guarded
        ra[j] = *(const float4*)(&A[(size_t)row * K + k0 + c4 * 4]);
      }
    } else {
      const unsigned short* A = (const unsigned short*)Ap;
#pragma unroll
      for (int j = 0; j < NA; ++j) {
        const int i = tid + j * 256;
        const int m = i / (BK / 8), c8 = i % (BK / 8);
        int row = row0 + m;
        if (row >= M) row = M - 1;
        ra[j] = *(const float4*)(&A[(size_t)row * K + k0 + c8 * 8]);
      }
    }
#pragma unroll
    for (int j = 0; j < NB; ++j) {
      const int i = tid + j * 256;
      const int n = i / (BK / 8), c8 = i % (BK / 8);
      rb[j] = *(const float4*)(&Bt[(size_t)n * K + k0 + c8 * 8]);
    }
  };
  auto store_lds = [&]() {
    if constexpr (!ABF16) {
#pragma unroll
      for (int j = 0; j < NA; ++j) {
        const int i = tid + j * 256;
        const int m = i / (BK / 4), c4 = i % (BK / 4);
        ushort4 h;
        h.x = f2bf(ra[j].x); h.y = f2bf(ra[j].y);
        h.z = f2bf(ra[j].z); h.w = f2bf(ra[j].w);
        const int byte = ((m * BK + c4 * 4) * 2) ^ ((m & 7) << 4);
        *(ushort4*)(as_ + byte) = h;
      }
    } else {
#pragma unroll
      for (int j = 0; j < NA; ++j) {
        const int i = tid + j * 256;
        const int m = i / (BK / 8), c8 = i % (BK / 8);
        const int byte = ((m * BK + c8 * 8) * 2) ^ ((m & 7) << 4);
        *(float4*)(as_ + byte) = ra[j];
      }
    }
#pragma unroll
    for (int j = 0; j < NB; ++j) {
      const int i = tid + j * 256;
      const int n = i / (BK / 8), c8 = i % (BK / 8);
      const int byte = ((n * BK + c8 * 8) * 2) ^ ((n & 7) << 4);
      *(float4*)(bs_ + byte) = rb[j];
    }
  };

  f32x4 acc[2][BN / 16];
#pragma unroll
  for (int a = 0; a < 2; ++a)
#pragma unroll
    for (int b = 0; b < BN / 16; ++b) acc[a][b] = (f32x4)0.f;

  const int nk = K / BK;
  fetch(0);
  for (int t = 0; t < nk; ++t) {
    store_lds();
    __syncthreads();
    if (t + 1 < nk) fetch((t + 1) * BK);  // loads in flight across MFMA + barrier
#pragma unroll
    for (int kk = 0; kk < BK; kk += 32) {
      const int koff = kk + lg * 8;
      const int ra0 = wid * 32 + l15;
      const int ra1 = ra0 + 16;
      const bf16x8 a0 = *(const bf16x8*)(as_ + (((ra0 * BK + koff) * 2) ^ ((ra0 & 7) << 4)));
      const bf16x8 a1 = *(const bf16x8*)(as_ + (((ra1 * BK + koff) * 2) ^ ((ra1 & 7) << 4)));
#pragma unroll
      for (int nf = 0; nf < BN / 16; ++nf) {
        const int n = nf * 16 + l15;
        const bf16x8 b = *(const bf16x8*)(bs_ + (((n * BK + koff) * 2) ^ ((n & 7) << 4)));
        acc[0][nf] = __builtin_amdgcn_mfma_f32_16x16x32_bf16(a0, b, acc[0][nf], 0, 0, 0);
        acc[1][nf] = __builtin_amdgcn_mfma_f32_16x16x32_bf16(a1, b, acc[1][nf], 0, 0, 0);
      }
    }
    __syncthreads();
  }
  // epilogue: transpose through LDS for coalesced bf16 stores
  unsigned short* outl = (unsigned short*)lds;
#pragma unroll
  for (int mf = 0; mf < 2; ++mf)
#pragma unroll
    for (int nf = 0; nf < BN / 16; ++nf)
#pragma unroll
      for (int r = 0; r < 4; ++r) {
        const int row = wid * 32 + mf * 16 + lg * 4 + r;  // D: row=(lane>>4)*4+r
        const int col = nf * 16 + l15;                    //    col=lane&15
        outl[row * OUTP + col] = f2bf(acc[mf][nf][r]);
      }
  __syncthreads();
#pragma unroll
  for (int i = tid; i < BM * (BN / 8); i += 256) {
    const int m = i / (BN / 8), c8 = i % (BN / 8);
    const int row = row0 + m;
    if (row < M)
      *(float4*)(&C[(size_t)row * BN + c8 * 8]) = *(const float4*)(&outl[m * OUTP + c8 * 8]);
  }
}

// ---------------- prep: W1^T, W3^T (bf16) — must precede GEMM1 ----------------
__global__ __launch_bounds__(256) void k_prep(const float* __restrict__ W1,
                                              const float* __restrict__ W3,
                                              unsigned short* __restrict__ w1t,
                                              unsigned short* __restrict__ w3t) {
  const int i = blockIdx.x * 256 + threadIdx.x;  // grid exact: PREP_NB
  if (i < DI * DH) {  // w1t[n][k] = W1[k][n]
    const int n = i / DI, k = i % DI;
    w1t[i] = f2bf(W1[k * DH + n]);
  } else {
    const int j = i - DI * DH;  // w3t[n][k] = W3[k][n]
    const int n = j / DH, k = j % DH;
    w3t[j] = f2bf(W3[k * DO + n]);
  }
}

// ---------------- fused: GEMM1 + rank (independent, both latency-bound) ----
// 1:8 interleave so both kinds populate CUs from dispatch start.
__global__ __launch_bounds__(256) void k_g1_rank(const float* __restrict__ x,
                                                 const unsigned short* __restrict__ w1t,
                                                 unsigned short* __restrict__ sup,
                                                 const int* __restrict__ erow,
                                                 int* __restrict__ cnt,
                                                 int* __restrict__ rank) {
  const int b = blockIdx.x;  // grid: G1_NB * 9 = 7038
  if (b % 9 == 0) {
    gemm_block<128, 128, 64, false>(x, w1t, sup, NN, DI, b / 9);
  } else {
    const int rb = (b / 9) * 8 + (b % 9) - 1;
    if (rb < RANK_NB) {
      const int e = rb * 256 + threadIdx.x;
      rank[e] = atomicAdd(&cnt[erow[e]], 1);
    }
  }
}

// ---------------- fused: GEMM2 + edot (both post-spmm1, independent) ------
__global__ __launch_bounds__(256) void k_g2_edot(const unsigned short* __restrict__ h1,
                                                 const unsigned short* __restrict__ w3t,
                                                 unsigned short* __restrict__ sup,
                                                 const int* __restrict__ ecol,
                                                 const float* __restrict__ eval,
                                                 const float* __restrict__ hw,
                                                 float* __restrict__ pzmu) {
  const int b = blockIdx.x;  // grid: G1_NB * 9 = 7038
  if (b % 9 == 0) {
    gemm_block<128, 64, 64, true>(h1, w3t, sup, NN, DH, b / 9);
  } else {
    const int eb = (b / 9) * 8 + (b % 9) - 1;
    if (eb < EDOT_NB) {
      __shared__ float red[256];
      const int i = eb * 256 + threadIdx.x;
      red[threadIdx.x] = eval[i] * hw[ecol[i]];
      __syncthreads();
      for (int off = 128; off > 0; off >>= 1) {
        if (threadIdx.x < off) red[threadIdx.x] += red[threadIdx.x + off];
        __syncthreads();
      }
      if (threadIdx.x == 0) pzmu[eb] = red[0];
    }
  }
}

// ---------------- scans ----------------
__global__ __launch_bounds__(256) void k_scan1(const int* __restrict__ cnt,
                                               int* __restrict__ bsum) {
  __shared__ int red[256];
  const int b = blockIdx.x, t = threadIdx.x;
  const int base = b * SCAN_CHUNK + t * 4;
  int s = 0;
#pragma unroll
  for (int j = 0; j < 4; ++j) {
    const int idx = base + j;
    if (idx < NN) s += cnt[idx];
  }
  red[t] = s;
  __syncthreads();
  for (int off = 128; off > 0; off >>= 1) {
    if (t < off) red[t] += red[t + off];
    __syncthreads();
  }
  if (t == 0) bsum[b] = red[0];
}

__global__ __launch_bounds__(128) void k_scan2(const int* __restrict__ bsum,
                                               int* __restrict__ boff,
                                               int* __restrict__ rowptr) {
  __shared__ int s[128];
  const int t = threadIdx.x;
  const int v = (t < SCAN_NB) ? bsum[t] : 0;
  s[t] = v;
  __syncthreads();
  for (int off = 1; off < 128; off <<= 1) {
    int x = 0;
    if (t >= off) x = s[t - off];
    __syncthreads();
    s[t] += x;
    __syncthreads();
  }
  if (t < SCAN_NB) boff[t] = s[t] - v;   // exclusive block offsets
  if (t == 127) rowptr[NN] = s[127];     // total == NE
}

__global__ __launch_bounds__(256) void k_scan3(const int* __restrict__ cnt,
                                               const int* __restrict__ boff,
                                               int* __restrict__ rowptr) {
  __shared__ int tsum[256];
  const int b = blockIdx.x, t = threadIdx.x;
  const int base = b * SCAN_CHUNK + t * 4;
  int v[4];
#pragma unroll
  for (int j = 0; j < 4; ++j) {
    const int idx = base + j;
    v[j] = (idx < NN) ? cnt[idx] : 0;
  }
  const int pre1 = v[0];
  const int pre2 = pre1 + v[1];
  const int pre3 = pre2 + v[2];
  const int s = pre3 + v[3];
  tsum[t] = s;
  __syncthreads();
  for (int off = 1; off < 256; off <<= 1) {
    int x = 0;
    if (t >= off) x = tsum[t - off];
    __syncthreads();
    tsum[t] += x;
    __syncthreads();
  }
  const int excl = tsum[t] - s + boff[b];
  const int w[4] = {excl, excl + pre1, excl + pre2, excl + pre3};
#pragma unroll
  for (int j = 0; j < 4; ++j) {
    const int idx = base + j;
    if (idx < NN) rowptr[idx] = w[j];
  }
}

// ------- fused: place (atomic-free) + w2sum -------
__global__ __launch_bounds__(256) void k_place_w2(
    const int* __restrict__ erow, const int* __restrict__ ecol,
    const float* __restrict__ eval, const int* __restrict__ rank,
    const int* __restrict__ rowptr, int2* __restrict__ cpk,
    const float* __restrict__ W2, float* __restrict__ w2s) {
  const int b = blockIdx.x;  // grid: RANK_NB + 1
  if (b < RANK_NB) {
    const int e = b * 256 + threadIdx.x;
    const int pos = rowptr[erow[e]] + rank[e];
    cpk[pos] = make_int2(ecol[e], __float_as_int(eval[e]));
  } else {
    const int k = threadIdx.x;
    if (k < DH) {
      float s = 0.f;
      for (int d = 0; d < DO; ++d) s += W2[k * DO + d];
      w2s[k] = s;
    }
  }
}

// ---------------- SPMM1: 16 lanes/row, unroll x2, packed edge stream ------
__global__ __launch_bounds__(256) void k_spmm1(const unsigned short* __restrict__ sup1,
                                               const int* __restrict__ rowptr,
                                               const int2* __restrict__ cpk,
                                               const float* __restrict__ w2s,
                                               unsigned short* __restrict__ h1,
                                               float* __restrict__ hw) {
  const int tid = threadIdx.x;
  const int lane = tid & 15;                       // 16 lanes x 8 bf16 = 128 ch
  const int r = blockIdx.x * 16 + (tid >> 4);      // grid exact: NN/16
  const int e0 = rowptr[r];
  const int e1 = rowptr[r + 1];
  const uint4* s8 = reinterpret_cast<const uint4*>(sup1);  // 16B = 8 bf16
  float a0[8] = {0.f, 0.f, 0.f, 0.f, 0.f, 0.f, 0.f, 0.f};
  float a1[8] = {0.f, 0.f, 0.f, 0.f, 0.f, 0.f, 0.f, 0.f};
  int e = e0;
  for (; e + 2 <= e1; e += 2) {
    const int2 p0 = cpk[e];
    const int2 p1 = cpk[e + 1];
    const uint4 g0 = s8[(size_t)p0.x * 16 + lane];
    const uint4 g1 = s8[(size_t)p1.x * 16 + lane];
    fma8(a0, g0, __int_as_float(p0.y));
    fma8(a1, g1, __int_as_float(p1.y));
  }
  if (e < e1) {
    const int2 p0 = cpk[e];
    const uint4 g0 = s8[(size_t)p0.x * 16 + lane];
    fma8(a0, g0, __int_as_float(p0.y));
  }
  float acc[8];
#pragma unroll
  for (int j = 0; j < 8; ++j) acc[j] = fmaxf(a0[j] + a1[j], 0.f);
  uint4 o;
  o.x = (unsigned)f2bf(acc[0]) | ((unsigned)f2bf(acc[1]) << 16);
  o.y = (unsigned)f2bf(acc[2]) | ((unsigned)f2bf(acc[3]) << 16);
  o.z = (unsigned)f2bf(acc[4]) | ((unsigned)f2bf(acc[5]) << 16);
  o.w = (unsigned)f2bf(acc[6]) | ((unsigned)f2bf(acc[7]) << 16);
  reinterpret_cast<uint4*>(h1)[(size_t)r * 16 + lane] = o;
  // hw[r] = relu_row . w2sum  (feeds the folded z_mu)
  const float4 wlo = reinterpret_cast<const float4*>(w2s)[lane * 2];
  const float4 whi = reinterpret_cast<const float4*>(w2s)[lane * 2 + 1];
  float p = acc[0] * wlo.x + acc[1] * wlo.y + acc[2] * wlo.z + acc[3] * wlo.w +
            acc[4] * whi.x + acc[5] * whi.y + acc[6] * whi.z + acc[7] * whi.w;
#pragma unroll
  for (int off = 8; off > 0; off >>= 1) p += __shfl_down(p, off, 16);
  if (lane == 0) hw[r] = p;
}

// ---------------- SPMM3 + exp + reduce (8 lanes/row, unroll x2) ----------
__global__ __launch_bounds__(256) void k_spmm3(const unsigned short* __restrict__ sup3,
                                               const int* __restrict__ rowptr,
                                               const int2* __restrict__ cpk,
                                               float* __restrict__ pexp) {
  const int tid = threadIdx.x;
  const int lane = tid & 7;
  const int r = blockIdx.x * 32 + (tid >> 3);  // grid exact: NN/32
  const int e0 = rowptr[r];
  const int e1 = rowptr[r + 1];
  const uint4* s8 = reinterpret_cast<const uint4*>(sup3);
  float a0[8] = {0.f, 0.f, 0.f, 0.f, 0.f, 0.f, 0.f, 0.f};
  float a1[8] = {0.f, 0.f, 0.f, 0.f, 0.f, 0.f, 0.f, 0.f};
  int e = e0;
  for (; e + 2 <= e1; e += 2) {
    const int2 p0 = cpk[e];
    const int2 p1 = cpk[e + 1];
    const uint4 g0 = s8[(size_t)p0.x * 8 + lane];
    const uint4 g1 = s8[(size_t)p1.x * 8 + lane];
    fma8(a0, g0, __int_as_float(p0.y));
    fma8(a1, g1, __int_as_float(p1.y));
  }
  if (e < e1) {
    const int2 p0 = cpk[e];
    const uint4 g0 = s8[(size_t)p0.x * 8 + lane];
    fma8(a0, g0, __int_as_float(p0.y));
  }
  float p = 0.f;
#pragma unroll
  for (int j = 0; j < 8; ++j) p += expf(a0[j] + a1[j]);
#pragma unroll
  for (int off = 4; off > 0; off >>= 1) p += __shfl_down(p, off, 8);
  __shared__ float part[32];
  if (lane == 0) part[tid >> 3] = p;
  __syncthreads();
  if (tid == 0) {
    float s = 0.f;
#pragma unroll
    for (int i = 0; i < 32; ++i) s += part[i];
    pexp[blockIdx.x] = s;
  }
}

// ---------------- finalize ----------------
__global__ __launch_bounds__(256) void k_final(const float* __restrict__ pzmu, int nz,
                                               const float* __restrict__ pexp, int ne,
                                               float* __restrict__ out) {
  __shared__ float red[256];
  const int t = threadIdx.x;
  float s1 = 0.f, s2 = 0.f;
  for (int i = t; i < nz; i += 256) s1 += pzmu[i];
  for (int i = t; i < ne; i += 256) s2 += pexp[i];
  red[t] = s1;
  __syncthreads();
  for (int off = 128; off > 0; off >>= 1) {
    if (t < off) red[t] += red[t + off];
    __syncthreads();
  }
  const float tot1 = red[0];
  __syncthreads();
  red[t] = s2;
  __syncthreads();
  for (int off = 128; off > 0; off >>= 1) {
    if (t < off) red[t] += red[t + off];
    __syncthreads();
  }
  if (t == 0) {
    const float denom = (float)NN * (float)DO;  // mean over [N, 64]
    out[0] = tot1 / denom;
    out[1] = logf(red[0] / denom);
  }
}

}  // namespace

extern "C" void kernel_launch(void* const* d_in, const int* in_sizes, int n_in,
                              void* d_out, int out_size, void* d_ws, size_t ws_size,
                              hipStream_t stream) {
  const float* x    = (const float*)d_in[0];
  const int*   erow = (const int*)d_in[1];
  const int*   ecol = (const int*)d_in[2];
  const float* eval = (const float*)d_in[3];
  const float* W1   = (const float*)d_in[4];
  const float* W2   = (const float*)d_in[5];
  const float* W3   = (const float*)d_in[6];
  float* out = (float*)d_out;

  // workspace carve-out (256B aligned); peak ~80 MB
  char* p = (char*)d_ws;
  auto alloc = [&](size_t bytes) -> void* {
    void* r = (void*)p;
    p += (bytes + 255) & ~(size_t)255;
    return r;
  };
  unsigned short* sup = (unsigned short*)alloc((size_t)NN * DH * 2);  // support1; reused as support3
  unsigned short* h1  = (unsigned short*)alloc((size_t)NN * DH * 2);  // h1 bf16
  int2*  cpk    = (int2*)alloc((size_t)NE * 8);   // packed (col, valbits)
  int*   rank   = (int*)alloc((size_t)NE * 4);
  int*   rowptr = (int*)alloc((size_t)(NN + 1) * 4);
  int*   cnt    = (int*)alloc((size_t)NN * 4);
  float* hw     = (float*)alloc((size_t)NN * 4);
  float* w2s    = (float*)alloc(DH * 4);
  unsigned short* w1t = (unsigned short*)alloc((size_t)DH * DI * 2);  // W1^T bf16 [128][256]
  unsigned short* w3t = (unsigned short*)alloc((size_t)DO * DH * 2);  // W3^T bf16 [64][128]
  int*   bsum   = (int*)alloc(SCAN_NB * 4);
  int*   boff   = (int*)alloc(SCAN_NB * 4);
  float* pexp   = (float*)alloc(SP3_NB * 4);
  float* pzmu   = (float*)alloc(EDOT_NB * 4);

  hipMemsetAsync(cnt, 0, (size_t)NN * 4, stream);

  // weight prep first (GEMM1 consumes w1t)
  k_prep<<<PREP_NB, 256, 0, stream>>>(W1, W3, w1t, w3t);

  // fused: GEMM1 (support1 = x@W1, MFMA, reg-prefetched) + rank atomics
  k_g1_rank<<<G1_NB * 9, 256, 0, stream>>>(x, w1t, sup, erow, cnt, rank);

  k_scan1<<<SCAN_NB, 256, 0, stream>>>(cnt, bsum);
  k_scan2<<<1, 128, 0, stream>>>(bsum, boff, rowptr);
  k_scan3<<<SCAN_NB, 256, 0, stream>>>(cnt, boff, rowptr);

  // place (atomic-free) + w2sum
  k_place_w2<<<RANK_NB + 1, 256, 0, stream>>>(erow, ecol, eval, rank, rowptr, cpk, W2, w2s);

  // h1 = relu(spmm(support1)) [bf16]; hw = h1 . w2sum   (mu branch folded)
  k_spmm1<<<NN / 16, 256, 0, stream>>>(sup, rowptr, cpk, w2s, h1, hw);

  // fused: GEMM2 (support3 = h1@W3, MFMA) + z_mu edge-dot partials
  k_g2_edot<<<G1_NB * 9, 256, 0, stream>>>(h1, w3t, sup, ecol, eval, hw, pzmu);

  // logvar spmm fused with sum(exp(.)) -> per-block partials
  k_spmm3<<<NN / 32, 256, 0, stream>>>(sup, rowptr, cpk, pexp);

  k_final<<<1, 256, 0, stream>>>(pzmu, EDOT_NB, pexp, SP3_NB, out);
}

// Round 7
// 235.335 us; speedup vs baseline: 2.6527x; 1.1133x over previous
//
#include <hip/hip_runtime.h>
#include <cstdint>
#include <cstddef>

namespace {

constexpr int NN = 100000;   // nodes
constexpr int NE = 1600000;  // edges
constexpr int DI = 256;
constexpr int DH = 128;
constexpr int DO = 64;
constexpr int SCAN_CHUNK = 1024;
constexpr int SCAN_NB = (NN + SCAN_CHUNK - 1) / SCAN_CHUNK;  // 98
constexpr int RANK_NB = NE / 256;   // 6250
constexpr int EDOT_NB = NE / 256;   // 6250
constexpr int SP3_NB = NN / 32;     // 3125
constexpr int G1_NB = (NN + 127) / 128;  // 782 gemm blocks
constexpr int PREP_NB = (DI * DH + DH * DO) / 256;  // 160

using bf16x8 = __attribute__((ext_vector_type(8))) short;  // 8 bf16 = 4 VGPR
using f32x4  = __attribute__((ext_vector_type(4))) float;

__device__ inline unsigned short f2bf(float f) {
  unsigned int u = __float_as_uint(f);
  u += 0x7FFFu + ((u >> 16) & 1u);  // round-to-nearest-even
  return (unsigned short)(u >> 16);
}
__device__ inline float bflo(unsigned int u) { return __uint_as_float(u << 16); }
__device__ inline float bfhi(unsigned int u) { return __uint_as_float(u & 0xffff0000u); }

__device__ inline void fma8(float* acc, const uint4 g, const float v) {
  acc[0] = fmaf(v, bflo(g.x), acc[0]); acc[1] = fmaf(v, bfhi(g.x), acc[1]);
  acc[2] = fmaf(v, bflo(g.y), acc[2]); acc[3] = fmaf(v, bfhi(g.y), acc[3]);
  acc[4] = fmaf(v, bflo(g.z), acc[4]); acc[5] = fmaf(v, bfhi(g.z), acc[5]);
  acc[6] = fmaf(v, bflo(g.w), acc[6]); acc[7] = fmaf(v, bfhi(g.w), acc[7]);
}

// async global->LDS, 16B per lane; LDS dest = wave-uniform base + lane*16
__device__ __forceinline__ void gl16(const void* g, void* l) {
  __builtin_amdgcn_global_load_lds(
      (const __attribute__((address_space(1))) void*)g,
      (__attribute__((address_space(3))) void*)l, 16, 0, 0);
}

__device__ __forceinline__ bf16x8 pack8(const f32x4 lo, const f32x4 hi) {
  bf16x8 r;
  r[0] = (short)f2bf(lo[0]); r[1] = (short)f2bf(lo[1]);
  r[2] = (short)f2bf(lo[2]); r[3] = (short)f2bf(lo[3]);
  r[4] = (short)f2bf(hi[0]); r[5] = (short)f2bf(hi[1]);
  r[6] = (short)f2bf(hi[2]); r[7] = (short)f2bf(hi[3]);
  return r;
}

// ---- MFMA GEMM block body: C[M][BN] = A[M][K] @ Bt[BN][K]^T (bf16 out) ----
// Staging via global_load_lds w=16; LDS linear, swizzle applied on the global
// SOURCE address (inverse) and on fragment reads: byte ^ ((row&7)<<4).
template <int BM, int BN, int BK, bool ABF16>
__device__ __forceinline__ void gemm_block(const void* __restrict__ Ap,
                                           const unsigned short* __restrict__ Bt,
                                           unsigned short* __restrict__ C,
                                           int M, int K, int bx) {
  constexpr int ABYT = ABF16 ? 2 : 4;
  constexpr int SBA = BK * ABYT;   // LDS A row stride bytes (256 f32 / 128 bf16)
  constexpr int SBB = BK * 2;      // 128
  constexpr int ASZ = BM * SBA;
  constexpr int BSZ = BN * SBB;
  constexpr int OUTP = BN + 8;     // padded epilogue stride (16B-aligned)
  constexpr int OUTB = BM * OUTP * 2;
  constexpr int STAGE = ASZ + BSZ;
  constexpr int LDSB = STAGE > OUTB ? STAGE : OUTB;
  __shared__ __align__(16) char lds[LDSB];
  char* const as_ = lds;
  char* const bs_ = lds + ASZ;

  const int tid = threadIdx.x;
  const int wid = tid >> 6;
  const int lane = tid & 63;
  const int l15 = lane & 15;
  const int lg = lane >> 4;            // 0..3
  const int msk = (l15 & 7) << 4;      // frag-read swizzle (row&7 == l15&7)
  const int row0 = bx * BM;

  constexpr int NGA = ASZ / (256 * 16);
  constexpr int NGB = BSZ / (256 * 16);
  const char* Ab = (const char*)Ap;
  const char* Bb = (const char*)Bt;

  f32x4 acc[2][BN / 16];
#pragma unroll
  for (int a = 0; a < 2; ++a)
#pragma unroll
    for (int b = 0; b < BN / 16; ++b) acc[a][b] = (f32x4)0.f;

  const int nk = K / BK;
  for (int t = 0; t < nk; ++t) {
    const int k0 = t * BK;
    // ---- stage A: linear LDS dest, inverse-swizzled global source ----
#pragma unroll
    for (int j = 0; j < NGA; ++j) {
      const int d = (j * 256 + tid) * 16;
      const int row = d / SBA;
      const int u = (d % SBA) ^ ((row & 7) << 4);
      int grow = row0 + row;
      if (grow >= M) grow = M - 1;  // clamp: harmless, stores guarded
      gl16(Ab + (size_t)grow * (size_t)(K * ABYT) + k0 * ABYT + u, as_ + d);
    }
    // ---- stage B ----
#pragma unroll
    for (int j = 0; j < NGB; ++j) {
      const int d = (j * 256 + tid) * 16;
      const int n = d / SBB;
      const int u = (d % SBB) ^ ((n & 7) << 4);
      gl16(Bb + (size_t)n * (size_t)(K * 2) + k0 * 2 + u, bs_ + d);
    }
    __syncthreads();  // compiler drains vmcnt before barrier
    // ---- MFMA inner loop ----
#pragma unroll
    for (int kk = 0; kk < BK; kk += 32) {
      const int koff = kk + lg * 8;
      bf16x8 a0, a1;
      if constexpr (!ABF16) {
        const int b0 = (wid * 32 + l15) * SBA + koff * 4;   // bit4 == 0
        const int b1 = b0 + 16 * SBA;                        // row +16, same msk
        const f32x4 q00 = *(const f32x4*)(as_ + (b0 ^ msk));
        const f32x4 q01 = *(const f32x4*)(as_ + ((b0 ^ msk) ^ 16));
        const f32x4 q10 = *(const f32x4*)(as_ + (b1 ^ msk));
        const f32x4 q11 = *(const f32x4*)(as_ + ((b1 ^ msk) ^ 16));
        a0 = pack8(q00, q01);
        a1 = pack8(q10, q11);
      } else {
        const int b0 = (wid * 32 + l15) * SBA + koff * 2;
        const int b1 = b0 + 16 * SBA;
        a0 = *(const bf16x8*)(as_ + (b0 ^ msk));
        a1 = *(const bf16x8*)(as_ + (b1 ^ msk));
      }
#pragma unroll
      for (int nf = 0; nf < BN / 16; ++nf) {
        const int n = nf * 16 + l15;
        const bf16x8 b = *(const bf16x8*)(bs_ + ((n * SBB + koff * 2) ^ msk));
        acc[0][nf] = __builtin_amdgcn_mfma_f32_16x16x32_bf16(a0, b, acc[0][nf], 0, 0, 0);
        acc[1][nf] = __builtin_amdgcn_mfma_f32_16x16x32_bf16(a1, b, acc[1][nf], 0, 0, 0);
      }
    }
    __syncthreads();
  }
  // ---- epilogue: transpose through LDS for coalesced bf16 stores ----
  unsigned short* outl = (unsigned short*)lds;
#pragma unroll
  for (int mf = 0; mf < 2; ++mf)
#pragma unroll
    for (int nf = 0; nf < BN / 16; ++nf)
#pragma unroll
      for (int r = 0; r < 4; ++r) {
        const int row = wid * 32 + mf * 16 + lg * 4 + r;  // D: row=(lane>>4)*4+r
        const int col = nf * 16 + l15;                    //    col=lane&15
        outl[row * OUTP + col] = f2bf(acc[mf][nf][r]);
      }
  __syncthreads();
#pragma unroll
  for (int i = tid; i < BM * (BN / 8); i += 256) {
    const int m = i / (BN / 8), c8 = i % (BN / 8);
    const int row = row0 + m;
    if (row < M)
      *(float4*)(&C[(size_t)row * BN + c8 * 8]) = *(const float4*)(&outl[m * OUTP + c8 * 8]);
  }
}

// ---------------- prep: W1^T, W3^T (bf16) — must precede GEMM1 ------------
__global__ __launch_bounds__(256) void k_prep(const float* __restrict__ W1,
                                              const float* __restrict__ W3,
                                              unsigned short* __restrict__ w1t,
                                              unsigned short* __restrict__ w3t) {
  const int i = blockIdx.x * 256 + threadIdx.x;  // grid exact: PREP_NB
  if (i < DI * DH) {  // w1t[n][k] = W1[k][n]
    const int n = i / DI, k = i % DI;
    w1t[i] = f2bf(W1[k * DH + n]);
  } else {
    const int j = i - DI * DH;  // w3t[n][k] = W3[k][n]
    const int n = j / DH, k = j % DH;
    w3t[j] = f2bf(W3[k * DO + n]);
  }
}

// ---------------- fused: GEMM1 + rank (independent, both latency-bound) ----
__global__ __launch_bounds__(256) void k_g1_rank(const float* __restrict__ x,
                                                 const unsigned short* __restrict__ w1t,
                                                 unsigned short* __restrict__ sup,
                                                 const int* __restrict__ erow,
                                                 int* __restrict__ cnt,
                                                 int* __restrict__ rank) {
  const int b = blockIdx.x;  // grid: G1_NB * 9 = 7038
  if (b % 9 == 0) {
    gemm_block<128, 128, 64, false>(x, w1t, sup, NN, DI, b / 9);
  } else {
    const int rb = (b / 9) * 8 + (b % 9) - 1;
    if (rb < RANK_NB) {
      const int e = rb * 256 + threadIdx.x;
      rank[e] = atomicAdd(&cnt[erow[e]], 1);
    }
  }
}

// ---------------- fused: GEMM2 + edot (both post-spmm1, independent) ------
__global__ __launch_bounds__(256) void k_g2_edot(const unsigned short* __restrict__ h1,
                                                 const unsigned short* __restrict__ w3t,
                                                 unsigned short* __restrict__ sup,
                                                 const int* __restrict__ ecol,
                                                 const float* __restrict__ eval,
                                                 const float* __restrict__ hw,
                                                 float* __restrict__ pzmu) {
  const int b = blockIdx.x;  // grid: G1_NB * 9 = 7038
  if (b % 9 == 0) {
    gemm_block<128, 64, 64, true>(h1, w3t, sup, NN, DH, b / 9);
  } else {
    const int eb = (b / 9) * 8 + (b % 9) - 1;
    if (eb < EDOT_NB) {
      __shared__ float red[256];
      const int i = eb * 256 + threadIdx.x;
      red[threadIdx.x] = eval[i] * hw[ecol[i]];
      __syncthreads();
      for (int off = 128; off > 0; off >>= 1) {
        if (threadIdx.x < off) red[threadIdx.x] += red[threadIdx.x + off];
        __syncthreads();
      }
      if (threadIdx.x == 0) pzmu[eb] = red[0];
    }
  }
}

// ---------------- scans ----------------
__global__ __launch_bounds__(256) void k_scan1(const int* __restrict__ cnt,
                                               int* __restrict__ bsum) {
  __shared__ int red[256];
  const int b = blockIdx.x, t = threadIdx.x;
  const int base = b * SCAN_CHUNK + t * 4;
  int s = 0;
#pragma unroll
  for (int j = 0; j < 4; ++j) {
    const int idx = base + j;
    if (idx < NN) s += cnt[idx];
  }
  red[t] = s;
  __syncthreads();
  for (int off = 128; off > 0; off >>= 1) {
    if (t < off) red[t] += red[t + off];
    __syncthreads();
  }
  if (t == 0) bsum[b] = red[0];
}

__global__ __launch_bounds__(128) void k_scan2(const int* __restrict__ bsum,
                                               int* __restrict__ boff,
                                               int* __restrict__ rowptr) {
  __shared__ int s[128];
  const int t = threadIdx.x;
  const int v = (t < SCAN_NB) ? bsum[t] : 0;
  s[t] = v;
  __syncthreads();
  for (int off = 1; off < 128; off <<= 1) {
    int x = 0;
    if (t >= off) x = s[t - off];
    __syncthreads();
    s[t] += x;
    __syncthreads();
  }
  if (t < SCAN_NB) boff[t] = s[t] - v;   // exclusive block offsets
  if (t == 127) rowptr[NN] = s[127];     // total == NE
}

__global__ __launch_bounds__(256) void k_scan3(const int* __restrict__ cnt,
                                               const int* __restrict__ boff,
                                               int* __restrict__ rowptr) {
  __shared__ int tsum[256];
  const int b = blockIdx.x, t = threadIdx.x;
  const int base = b * SCAN_CHUNK + t * 4;
  int v[4];
#pragma unroll
  for (int j = 0; j < 4; ++j) {
    const int idx = base + j;
    v[j] = (idx < NN) ? cnt[idx] : 0;
  }
  const int pre1 = v[0];
  const int pre2 = pre1 + v[1];
  const int pre3 = pre2 + v[2];
  const int s = pre3 + v[3];
  tsum[t] = s;
  __syncthreads();
  for (int off = 1; off < 256; off <<= 1) {
    int x = 0;
    if (t >= off) x = tsum[t - off];
    __syncthreads();
    tsum[t] += x;
    __syncthreads();
  }
  const int excl = tsum[t] - s + boff[b];
  const int w[4] = {excl, excl + pre1, excl + pre2, excl + pre3};
#pragma unroll
  for (int j = 0; j < 4; ++j) {
    const int idx = base + j;
    if (idx < NN) rowptr[idx] = w[j];
  }
}

// ------- fused: place (atomic-free) + w2sum -------
__global__ __launch_bounds__(256) void k_place_w2(
    const int* __restrict__ erow, const int* __restrict__ ecol,
    const float* __restrict__ eval, const int* __restrict__ rank,
    const int* __restrict__ rowptr, int2* __restrict__ cpk,
    const float* __restrict__ W2, float* __restrict__ w2s) {
  const int b = blockIdx.x;  // grid: RANK_NB + 1
  if (b < RANK_NB) {
    const int e = b * 256 + threadIdx.x;
    const int pos = rowptr[erow[e]] + rank[e];
    cpk[pos] = make_int2(ecol[e], __float_as_int(eval[e]));
  } else {
    const int k = threadIdx.x;
    if (k < DH) {
      float s = 0.f;
      for (int d = 0; d < DO; ++d) s += W2[k * DO + d];
      w2s[k] = s;
    }
  }
}

// ---------------- SPMM1: 16 lanes/row, 4-deep unroll ----------------------
__global__ __launch_bounds__(256) void k_spmm1(const unsigned short* __restrict__ sup1,
                                               const int* __restrict__ rowptr,
                                               const int2* __restrict__ cpk,
                                               const float* __restrict__ w2s,
                                               unsigned short* __restrict__ h1,
                                               float* __restrict__ hw) {
  const int tid = threadIdx.x;
  const int lane = tid & 15;                       // 16 lanes x 8 bf16 = 128 ch
  const int r = blockIdx.x * 16 + (tid >> 4);      // grid exact: NN/16
  const int e0 = rowptr[r];
  const int e1 = rowptr[r + 1];
  const uint4* s8 = reinterpret_cast<const uint4*>(sup1);  // 16B = 8 bf16
  float aA[8] = {0,0,0,0,0,0,0,0}, aB[8] = {0,0,0,0,0,0,0,0};
  float aC[8] = {0,0,0,0,0,0,0,0}, aD[8] = {0,0,0,0,0,0,0,0};
  int e = e0;
  for (; e + 4 <= e1; e += 4) {
    const int2 p0 = cpk[e],     p1 = cpk[e + 1];
    const int2 p2 = cpk[e + 2], p3 = cpk[e + 3];
    const uint4 g0 = s8[(size_t)p0.x * 16 + lane];
    const uint4 g1 = s8[(size_t)p1.x * 16 + lane];
    const uint4 g2 = s8[(size_t)p2.x * 16 + lane];
    const uint4 g3 = s8[(size_t)p3.x * 16 + lane];
    fma8(aA, g0, __int_as_float(p0.y));
    fma8(aB, g1, __int_as_float(p1.y));
    fma8(aC, g2, __int_as_float(p2.y));
    fma8(aD, g3, __int_as_float(p3.y));
  }
  if (e + 2 <= e1) {
    const int2 p0 = cpk[e], p1 = cpk[e + 1];
    const uint4 g0 = s8[(size_t)p0.x * 16 + lane];
    const uint4 g1 = s8[(size_t)p1.x * 16 + lane];
    fma8(aA, g0, __int_as_float(p0.y));
    fma8(aB, g1, __int_as_float(p1.y));
    e += 2;
  }
  if (e < e1) {
    const int2 p0 = cpk[e];
    const uint4 g0 = s8[(size_t)p0.x * 16 + lane];
    fma8(aC, g0, __int_as_float(p0.y));
  }
  float acc[8];
#pragma unroll
  for (int j = 0; j < 8; ++j) acc[j] = fmaxf((aA[j] + aB[j]) + (aC[j] + aD[j]), 0.f);
  uint4 o;
  o.x = (unsigned)f2bf(acc[0]) | ((unsigned)f2bf(acc[1]) << 16);
  o.y = (unsigned)f2bf(acc[2]) | ((unsigned)f2bf(acc[3]) << 16);
  o.z = (unsigned)f2bf(acc[4]) | ((unsigned)f2bf(acc[5]) << 16);
  o.w = (unsigned)f2bf(acc[6]) | ((unsigned)f2bf(acc[7]) << 16);
  reinterpret_cast<uint4*>(h1)[(size_t)r * 16 + lane] = o;
  // hw[r] = relu_row . w2sum  (feeds the folded z_mu)
  const float4 wlo = reinterpret_cast<const float4*>(w2s)[lane * 2];
  const float4 whi = reinterpret_cast<const float4*>(w2s)[lane * 2 + 1];
  float p = acc[0] * wlo.x + acc[1] * wlo.y + acc[2] * wlo.z + acc[3] * wlo.w +
            acc[4] * whi.x + acc[5] * whi.y + acc[6] * whi.z + acc[7] * whi.w;
#pragma unroll
  for (int off = 8; off > 0; off >>= 1) p += __shfl_down(p, off, 16);
  if (lane == 0) hw[r] = p;
}

// ---------------- SPMM3 + exp + reduce (8 lanes/row, 4-deep unroll) -------
__global__ __launch_bounds__(256) void k_spmm3(const unsigned short* __restrict__ sup3,
                                               const int* __restrict__ rowptr,
                                               const int2* __restrict__ cpk,
                                               float* __restrict__ pexp) {
  const int tid = threadIdx.x;
  const int lane = tid & 7;
  const int r = blockIdx.x * 32 + (tid >> 3);  // grid exact: NN/32
  const int e0 = rowptr[r];
  const int e1 = rowptr[r + 1];
  const uint4* s8 = reinterpret_cast<const uint4*>(sup3);
  float aA[8] = {0,0,0,0,0,0,0,0}, aB[8] = {0,0,0,0,0,0,0,0};
  float aC[8] = {0,0,0,0,0,0,0,0}, aD[8] = {0,0,0,0,0,0,0,0};
  int e = e0;
  for (; e + 4 <= e1; e += 4) {
    const int2 p0 = cpk[e],     p1 = cpk[e + 1];
    const int2 p2 = cpk[e + 2], p3 = cpk[e + 3];
    const uint4 g0 = s8[(size_t)p0.x * 8 + lane];
    const uint4 g1 = s8[(size_t)p1.x * 8 + lane];
    const uint4 g2 = s8[(size_t)p2.x * 8 + lane];
    const uint4 g3 = s8[(size_t)p3.x * 8 + lane];
    fma8(aA, g0, __int_as_float(p0.y));
    fma8(aB, g1, __int_as_float(p1.y));
    fma8(aC, g2, __int_as_float(p2.y));
    fma8(aD, g3, __int_as_float(p3.y));
  }
  if (e + 2 <= e1) {
    const int2 p0 = cpk[e], p1 = cpk[e + 1];
    const uint4 g0 = s8[(size_t)p0.x * 8 + lane];
    const uint4 g1 = s8[(size_t)p1.x * 8 + lane];
    fma8(aA, g0, __int_as_float(p0.y));
    fma8(aB, g1, __int_as_float(p1.y));
    e += 2;
  }
  if (e < e1) {
    const int2 p0 = cpk[e];
    const uint4 g0 = s8[(size_t)p0.x * 8 + lane];
    fma8(aC, g0, __int_as_float(p0.y));
  }
  float p = 0.f;
#pragma unroll
  for (int j = 0; j < 8; ++j) p += expf((aA[j] + aB[j]) + (aC[j] + aD[j]));
#pragma unroll
  for (int off = 4; off > 0; off >>= 1) p += __shfl_down(p, off, 8);
  __shared__ float part[32];
  if (lane == 0) part[tid >> 3] = p;
  __syncthreads();
  if (tid == 0) {
    float s = 0.f;
#pragma unroll
    for (int i = 0; i < 32; ++i) s += part[i];
    pexp[blockIdx.x] = s;
  }
}

// ---------------- finalize ----------------
__global__ __launch_bounds__(256) void k_final(const float* __restrict__ pzmu, int nz,
                                               const float* __restrict__ pexp, int ne,
                                               float* __restrict__ out) {
  __shared__ float red[256];
  const int t = threadIdx.x;
  float s1 = 0.f, s2 = 0.f;
  for (int i = t; i < nz; i += 256) s1 += pzmu[i];
  for (int i = t; i < ne; i += 256) s2 += pexp[i];
  red[t] = s1;
  __syncthreads();
  for (int off = 128; off > 0; off >>= 1) {
    if (t < off) red[t] += red[t + off];
    __syncthreads();
  }
  const float tot1 = red[0];
  __syncthreads();
  red[t] = s2;
  __syncthreads();
  for (int off = 128; off > 0; off >>= 1) {
    if (t < off) red[t] += red[t + off];
    __syncthreads();
  }
  if (t == 0) {
    const float denom = (float)NN * (float)DO;  // mean over [N, 64]
    out[0] = tot1 / denom;
    out[1] = logf(red[0] / denom);
  }
}

}  // namespace

extern "C" void kernel_launch(void* const* d_in, const int* in_sizes, int n_in,
                              void* d_out, int out_size, void* d_ws, size_t ws_size,
                              hipStream_t stream) {
  const float* x    = (const float*)d_in[0];
  const int*   erow = (const int*)d_in[1];
  const int*   ecol = (const int*)d_in[2];
  const float* eval = (const float*)d_in[3];
  const float* W1   = (const float*)d_in[4];
  const float* W2   = (const float*)d_in[5];
  const float* W3   = (const float*)d_in[6];
  float* out = (float*)d_out;

  // workspace carve-out (256B aligned); peak ~80 MB
  char* p = (char*)d_ws;
  auto alloc = [&](size_t bytes) -> void* {
    void* r = (void*)p;
    p += (bytes + 255) & ~(size_t)255;
    return r;
  };
  unsigned short* sup = (unsigned short*)alloc((size_t)NN * DH * 2);  // support1; reused as support3
  unsigned short* h1  = (unsigned short*)alloc((size_t)NN * DH * 2);  // h1 bf16
  int2*  cpk    = (int2*)alloc((size_t)NE * 8);   // packed (col, valbits)
  int*   rank   = (int*)alloc((size_t)NE * 4);
  int*   rowptr = (int*)alloc((size_t)(NN + 1) * 4);
  int*   cnt    = (int*)alloc((size_t)NN * 4);
  float* hw     = (float*)alloc((size_t)NN * 4);
  float* w2s    = (float*)alloc(DH * 4);
  unsigned short* w1t = (unsigned short*)alloc((size_t)DH * DI * 2);  // W1^T bf16 [128][256]
  unsigned short* w3t = (unsigned short*)alloc((size_t)DO * DH * 2);  // W3^T bf16 [64][128]
  int*   bsum   = (int*)alloc(SCAN_NB * 4);
  int*   boff   = (int*)alloc(SCAN_NB * 4);
  float* pexp   = (float*)alloc(SP3_NB * 4);
  float* pzmu   = (float*)alloc(EDOT_NB * 4);

  hipMemsetAsync(cnt, 0, (size_t)NN * 4, stream);

  // weight prep first (GEMM1 consumes w1t)
  k_prep<<<PREP_NB, 256, 0, stream>>>(W1, W3, w1t, w3t);

  // fused: GEMM1 (support1 = x@W1, gload_lds-staged MFMA) + rank atomics
  k_g1_rank<<<G1_NB * 9, 256, 0, stream>>>(x, w1t, sup, erow, cnt, rank);

  k_scan1<<<SCAN_NB, 256, 0, stream>>>(cnt, bsum);
  k_scan2<<<1, 128, 0, stream>>>(bsum, boff, rowptr);
  k_scan3<<<SCAN_NB, 256, 0, stream>>>(cnt, boff, rowptr);

  // place (atomic-free) + w2sum
  k_place_w2<<<RANK_NB + 1, 256, 0, stream>>>(erow, ecol, eval, rank, rowptr, cpk, W2, w2s);

  // h1 = relu(spmm(support1)) [bf16]; hw = h1 . w2sum   (mu branch folded)
  k_spmm1<<<NN / 16, 256, 0, stream>>>(sup, rowptr, cpk, w2s, h1, hw);

  // fused: GEMM2 (support3 = h1@W3, MFMA) + z_mu edge-dot partials
  k_g2_edot<<<G1_NB * 9, 256, 0, stream>>>(h1, w3t, sup, ecol, eval, hw, pzmu);

  // logvar spmm fused with sum(exp(.)) -> per-block partials
  k_spmm3<<<NN / 32, 256, 0, stream>>>(sup, rowptr, cpk, pexp);

  k_final<<<1, 256, 0, stream>>>(pzmu, EDOT_NB, pexp, SP3_NB, out);
}